// Round 1
// baseline (9958.385 us; speedup 1.0000x reference)
//
#include <hip/hip_runtime.h>
#include <math.h>

#define BB   8
#define SS   1024
#define EE   512
#define HH   8
#define DHH  64
#define LLY  2
#define CC   8921
#define DFF_ 2048

// ---------------------------------------------------------------------------
// embed: x[b,s,e] = inputs[b,s,e]*sqrt(E) + pe[b,e]   (pe indexed by batch — source bug kept)
// ---------------------------------------------------------------------------
__global__ __launch_bounds__(256) void embed_kernel(const float* __restrict__ in,
                                                    const float* __restrict__ pe,
                                                    float* __restrict__ x)
{
    const long i  = (long)blockIdx.x * 256 + threadIdx.x;   // float4 index over [B,S,E/4]
    const int  e4 = (int)(i & 127);                          // E/4 = 128
    const int  b  = (int)(i >> 17);                          // / (S*E/4) = 131072
    float4 v = ((const float4*)in)[i];
    const float4 p = ((const float4*)pe)[b * 128 + e4];
    const float sc = 22.627416997969522f;                    // sqrt(512)
    v.x = v.x * sc + p.x;  v.y = v.y * sc + p.y;
    v.z = v.z * sc + p.z;  v.w = v.w * sc + p.w;
    ((float4*)x)[i] = v;
}

// ---------------------------------------------------------------------------
// Generic fp32 GEMM: C[m,n] = act( A[m,:] . Bw[n,:] + bias[n] )
// A [M,K] row-major, Bw [N,K] row-major (i.e. C = A @ Bw^T).
// 64x64 tile, K-step 16, 16x16 threads, 4x4 per thread.
// act: 0=none, 1=relu, 2=tanh
// ---------------------------------------------------------------------------
__global__ __launch_bounds__(256) void gemm_atb(const float* __restrict__ A,
                                                const float* __restrict__ Bw,
                                                const float* __restrict__ bias,
                                                float* __restrict__ C,
                                                int M, int N, int K,
                                                long sAz, long sBz, long sCz,
                                                int act)
{
    __shared__ float As[16][64];
    __shared__ float Bs[16][64];
    const int tx = threadIdx.x, ty = threadIdx.y;
    const int tid = ty * 16 + tx;
    const int m0 = blockIdx.x * 64, n0 = blockIdx.y * 64;
    const float* Ab = A  + (long)blockIdx.z * sAz;
    const float* Bb = Bw + (long)blockIdx.z * sBz;
    float*       Cb = C  + (long)blockIdx.z * sCz;

    float acc[4][4] = {};
    const int lr = tid >> 2;          // 0..63
    const int lk = (tid & 3) << 2;    // 0,4,8,12

    for (int k0 = 0; k0 < K; k0 += 16) {
        float4 av = {0.f,0.f,0.f,0.f}, bv = {0.f,0.f,0.f,0.f};
        const int gm = m0 + lr;
        if (gm < M) av = *(const float4*)(Ab + (long)gm * K + k0 + lk);
        const int gn = n0 + lr;
        if (gn < N) bv = *(const float4*)(Bb + (long)gn * K + k0 + lk);
        As[lk + 0][lr] = av.x; As[lk + 1][lr] = av.y;
        As[lk + 2][lr] = av.z; As[lk + 3][lr] = av.w;
        Bs[lk + 0][lr] = bv.x; Bs[lk + 1][lr] = bv.y;
        Bs[lk + 2][lr] = bv.z; Bs[lk + 3][lr] = bv.w;
        __syncthreads();
        #pragma unroll
        for (int kk = 0; kk < 16; ++kk) {
            float a[4], b[4];
            *(float4*)a = *(const float4*)&As[kk][ty << 2];
            *(float4*)b = *(const float4*)&Bs[kk][tx << 2];
            #pragma unroll
            for (int i = 0; i < 4; ++i)
                #pragma unroll
                for (int j = 0; j < 4; ++j)
                    acc[i][j] = fmaf(a[i], b[j], acc[i][j]);
        }
        __syncthreads();
    }

    #pragma unroll
    for (int i = 0; i < 4; ++i) {
        const int gm = m0 + (ty << 2) + i;
        if (gm >= M) continue;
        #pragma unroll
        for (int j = 0; j < 4; ++j) {
            const int gn = n0 + (tx << 2) + j;
            if (gn >= N) continue;
            float v = acc[i][j];
            if (bias) v += bias[gn];
            if (act == 1)      v = fmaxf(v, 0.f);
            else if (act == 2) v = tanhf(v);
            Cb[(long)gm * N + gn] = v;
        }
    }
}

// ---------------------------------------------------------------------------
// Encoder self-attention: per (b,h), 8 q-rows per block; scores kept in regs.
// qkv layout [B,S,3E]; o layout [B,S,E].
// ---------------------------------------------------------------------------
__global__ __launch_bounds__(256) void attn_kernel(const float* __restrict__ qkv,
                                                   float* __restrict__ o)
{
    const int bh = blockIdx.y;         // b*H + h
    const int b  = bh >> 3, h = bh & 7;
    const int q0 = blockIdx.x << 3;    // 8 q rows
    __shared__ float sP[8][1028];      // padded to kill bank conflicts
    __shared__ float sQ[8][68];
    const int t = threadIdx.x;
    {
        const int r  = t >> 5;          // 0..7
        const int c2 = (t & 31) << 1;   // 0..62
        *(float2*)&sQ[r][c2] =
            *(const float2*)(qkv + ((long)(b * SS + q0 + r) * (3 * EE)) + h * DHH + c2);
    }
    __syncthreads();
    const int r  = t >> 5;
    const int ci = t & 31;

    float sc[32];
    const float* kbase = qkv + (long)b * SS * (3 * EE) + EE + h * DHH;
    #pragma unroll
    for (int j = 0; j < 32; ++j) {
        const int s = ci + (j << 5);
        const float* kp = kbase + (long)s * (3 * EE);
        float acc = 0.f;
        #pragma unroll
        for (int d = 0; d < DHH; d += 4) {
            const float4 kv = *(const float4*)(kp + d);
            const float4 qv = *(const float4*)&sQ[r][d];
            acc = fmaf(qv.x, kv.x, fmaf(qv.y, kv.y, fmaf(qv.z, kv.z, fmaf(qv.w, kv.w, acc))));
        }
        sc[j] = acc * 0.125f;           // 1/sqrt(64)
    }
    float mx = -1e30f;
    #pragma unroll
    for (int j = 0; j < 32; ++j) mx = fmaxf(mx, sc[j]);
    #pragma unroll
    for (int off = 1; off < 32; off <<= 1) mx = fmaxf(mx, __shfl_xor(mx, off));
    float sum = 0.f;
    #pragma unroll
    for (int j = 0; j < 32; ++j) { sc[j] = __expf(sc[j] - mx); sum += sc[j]; }
    #pragma unroll
    for (int off = 1; off < 32; off <<= 1) sum += __shfl_xor(sum, off);
    const float inv = 1.f / sum;
    #pragma unroll
    for (int j = 0; j < 32; ++j) sP[r][ci + (j << 5)] = sc[j];
    __syncthreads();

    float2 accv = {0.f, 0.f};
    const float* vbase = qkv + (long)b * SS * (3 * EE) + 2 * EE + h * DHH + (ci << 1);
    #pragma unroll 8
    for (int s = 0; s < SS; ++s) {
        const float p = sP[r][s];
        const float2 vv = *(const float2*)(vbase + (long)s * (3 * EE));
        accv.x = fmaf(p, vv.x, accv.x);
        accv.y = fmaf(p, vv.y, accv.y);
    }
    accv.x *= inv; accv.y *= inv;
    *(float2*)(o + ((long)(b * SS + q0 + r) * EE) + h * DHH + (ci << 1)) = accv;
}

// ---------------------------------------------------------------------------
// Fused residual + LayerNorm, in place:  x = LN(x + o) * g + b   (row = B*S, E=512)
// ---------------------------------------------------------------------------
__global__ __launch_bounds__(256) void ln_fused(float* __restrict__ x,
                                                const float* __restrict__ o,
                                                const float* __restrict__ g,
                                                const float* __restrict__ bta)
{
    const long row = blockIdx.x;
    float* xr = x + row * EE;
    const float* orr = o + row * EE;
    const int t = threadIdx.x;
    const float v0 = xr[t] + orr[t];
    const float v1 = xr[t + 256] + orr[t + 256];
    float s = v0 + v1;
    #pragma unroll
    for (int off = 1; off < 64; off <<= 1) s += __shfl_xor(s, off);
    __shared__ float r1[4], r2[4];
    if ((t & 63) == 0) r1[t >> 6] = s;
    __syncthreads();
    const float mu = (r1[0] + r1[1] + r1[2] + r1[3]) * (1.f / EE);
    const float d0 = v0 - mu, d1 = v1 - mu;
    float q = d0 * d0 + d1 * d1;
    #pragma unroll
    for (int off = 1; off < 64; off <<= 1) q += __shfl_xor(q, off);
    if ((t & 63) == 0) r2[t >> 6] = q;
    __syncthreads();
    const float rs = rsqrtf((r2[0] + r2[1] + r2[2] + r2[3]) * (1.f / EE) + 1e-5f);
    xr[t]       = d0 * rs * g[t]       + bta[t];
    xr[t + 256] = d1 * rs * g[t + 256] + bta[t + 256];
}

// ---------------------------------------------------------------------------
// Label softmax over seq dim: attn[b,c,:] = softmax(attn[b,c,:]), rows = B*C, S=1024
// ---------------------------------------------------------------------------
__global__ __launch_bounds__(256) void label_softmax(float* __restrict__ attn)
{
    const long row = blockIdx.x;
    float* p = attn + row * (long)SS;
    const int t = threadIdx.x;
    float4 v = ((float4*)p)[t];
    __shared__ float red[4];
    float mx = fmaxf(fmaxf(v.x, v.y), fmaxf(v.z, v.w));
    #pragma unroll
    for (int off = 1; off < 64; off <<= 1) mx = fmaxf(mx, __shfl_xor(mx, off));
    if ((t & 63) == 0) red[t >> 6] = mx;
    __syncthreads();
    mx = fmaxf(fmaxf(red[0], red[1]), fmaxf(red[2], red[3]));
    v.x = __expf(v.x - mx); v.y = __expf(v.y - mx);
    v.z = __expf(v.z - mx); v.w = __expf(v.w - mx);
    float s = v.x + v.y + v.z + v.w;
    #pragma unroll
    for (int off = 1; off < 64; off <<= 1) s += __shfl_xor(s, off);
    __syncthreads();
    if ((t & 63) == 0) red[t >> 6] = s;
    __syncthreads();
    const float inv = 1.f / (red[0] + red[1] + red[2] + red[3]);
    v.x *= inv; v.y *= inv; v.z *= inv; v.w *= inv;
    ((float4*)p)[t] = v;
}

// ---------------------------------------------------------------------------
// outputs init: out[b,c] = fc_b[c]
// ---------------------------------------------------------------------------
__global__ __launch_bounds__(256) void init_out(float* __restrict__ out,
                                                const float* __restrict__ fcb)
{
    const int i = blockIdx.x * 256 + threadIdx.x;
    if (i < BB * CC) out[i] = fcb[i % CC];
}

// ---------------------------------------------------------------------------
// Fused label-output GEMM:
//   D[c,s] = fc_w[c,:] . x[b,s,:]   (64x64 tile like gemm_atb)
//   out[b,c] += sum_s attn[b,c,s] * D[c,s]     (epilogue: mult, shfl-reduce, atomicAdd)
// ---------------------------------------------------------------------------
__global__ __launch_bounds__(256) void gemm_label_out(const float* __restrict__ A,    // fc_w [C,E]
                                                      const float* __restrict__ Bx,   // x [B,S,E]
                                                      const float* __restrict__ attn, // [B,C,S]
                                                      float* __restrict__ out)        // [B,C]
{
    __shared__ float As[16][64];
    __shared__ float Bs[16][64];
    const int tx = threadIdx.x, ty = threadIdx.y;
    const int tid = ty * 16 + tx;
    const int m0 = blockIdx.x * 64, n0 = blockIdx.y * 64;
    const int b = blockIdx.z;
    const float* Bb   = Bx   + (long)b * SS * EE;
    const float* attb = attn + (long)b * CC * SS;
    float*       outb = out  + (long)b * CC;

    float acc[4][4] = {};
    const int lr = tid >> 2;
    const int lk = (tid & 3) << 2;

    for (int k0 = 0; k0 < EE; k0 += 16) {
        float4 av = {0.f,0.f,0.f,0.f};
        const int gm = m0 + lr;
        if (gm < CC) av = *(const float4*)(A + (long)gm * EE + k0 + lk);
        const float4 bv = *(const float4*)(Bb + (long)(n0 + lr) * EE + k0 + lk);
        As[lk + 0][lr] = av.x; As[lk + 1][lr] = av.y;
        As[lk + 2][lr] = av.z; As[lk + 3][lr] = av.w;
        Bs[lk + 0][lr] = bv.x; Bs[lk + 1][lr] = bv.y;
        Bs[lk + 2][lr] = bv.z; Bs[lk + 3][lr] = bv.w;
        __syncthreads();
        #pragma unroll
        for (int kk = 0; kk < 16; ++kk) {
            float a[4], bcol[4];
            *(float4*)a    = *(const float4*)&As[kk][ty << 2];
            *(float4*)bcol = *(const float4*)&Bs[kk][tx << 2];
            #pragma unroll
            for (int i = 0; i < 4; ++i)
                #pragma unroll
                for (int j = 0; j < 4; ++j)
                    acc[i][j] = fmaf(a[i], bcol[j], acc[i][j]);
        }
        __syncthreads();
    }

    float part[4];
    #pragma unroll
    for (int i = 0; i < 4; ++i) {
        const int c = m0 + (ty << 2) + i;
        float p = 0.f;
        if (c < CC) {
            const float4 aw = *(const float4*)(attb + (long)c * SS + n0 + (tx << 2));
            p = acc[i][0] * aw.x + acc[i][1] * aw.y + acc[i][2] * aw.z + acc[i][3] * aw.w;
        }
        #pragma unroll
        for (int off = 1; off < 16; off <<= 1) p += __shfl_xor(p, off);
        part[i] = p;
    }
    if (tx == 0) {
        #pragma unroll
        for (int i = 0; i < 4; ++i) {
            const int c = m0 + (ty << 2) + i;
            if (c < CC) atomicAdd(&outb[c], part[i]);
        }
    }
}

// ---------------------------------------------------------------------------
extern "C" void kernel_launch(void* const* d_in, const int* in_sizes, int n_in,
                              void* d_out, int out_size, void* d_ws, size_t ws_size,
                              hipStream_t stream)
{
    const float* inp   = (const float*)d_in[0];
    const float* pe    = (const float*)d_in[1];
    const float* label = (const float*)d_in[2];
    const float* l1w   = (const float*)d_in[3];
    const float* l1b   = (const float*)d_in[4];
    const float* fcw   = (const float*)d_in[5];
    const float* fcb   = (const float*)d_in[6];
    const float* ipw   = (const float*)d_in[7];
    const float* ipb   = (const float*)d_in[8];
    const float* opw   = (const float*)d_in[9];
    const float* opb   = (const float*)d_in[10];
    const float* g1    = (const float*)d_in[11];
    const float* b1    = (const float*)d_in[12];
    const float* g2    = (const float*)d_in[13];
    const float* b2    = (const float*)d_in[14];
    const float* w1    = (const float*)d_in[15];
    const float* bb1   = (const float*)d_in[16];
    const float* w2    = (const float*)d_in[17];
    const float* bb2   = (const float*)d_in[18];

    float* x    = (float*)d_ws;                       // [B,S,E]   = 4,194,304 f
    float* buf1 = x + (long)BB * SS * EE;             // [B,S,DFF] = 16,777,216 f (qkv/proj/ff1)
    float* buf2 = buf1 + (long)BB * SS * DFF_;        // [B,S,E]   = 4,194,304 f (o/ff2/o1)

    float* out0  = (float*)d_out;                     // [B,C]
    float* attnW = out0 + BB * CC;                    // [B,C,S]

    const dim3 thr(16, 16);
    const int M = BB * SS;                            // 8192

    embed_kernel<<<4096, 256, 0, stream>>>(inp, pe, x);

    for (int l = 0; l < LLY; ++l) {
        // qkv = x @ in_proj_w^T + in_proj_b          [8192, 1536]
        gemm_atb<<<dim3(128, 24, 1), thr, 0, stream>>>(x, ipw + (long)l * 3 * EE * EE,
                                                       ipb + l * 3 * EE, buf1,
                                                       M, 3 * EE, EE, 0, 0, 0, 0);
        // self-attention -> buf2
        attn_kernel<<<dim3(128, 64), 256, 0, stream>>>(buf1, buf2);
        // out proj -> buf1 (qkv dead)
        gemm_atb<<<dim3(128, 8, 1), thr, 0, stream>>>(buf2, opw + (long)l * EE * EE,
                                                      opb + l * EE, buf1,
                                                      M, EE, EE, 0, 0, 0, 0);
        ln_fused<<<M, 256, 0, stream>>>(x, buf1, g1 + l * EE, b1 + l * EE);
        // ff1 = relu(x @ w1^T + b1)  [8192, 2048] -> buf1
        gemm_atb<<<dim3(128, 32, 1), thr, 0, stream>>>(x, w1 + (long)l * DFF_ * EE,
                                                       bb1 + l * DFF_, buf1,
                                                       M, DFF_, EE, 0, 0, 0, 1);
        // ff2 = ff1 @ w2^T + b2      [8192, 512] -> buf2
        gemm_atb<<<dim3(128, 8, 1), thr, 0, stream>>>(buf1, w2 + (long)l * EE * DFF_,
                                                      bb2 + l * EE, buf2,
                                                      M, EE, DFF_, 0, 0, 0, 0);
        ln_fused<<<M, 256, 0, stream>>>(x, buf2, g2 + l * EE, b2 + l * EE);
    }

    // o1 = tanh(x @ l1_w^T + l1_b) -> buf2
    gemm_atb<<<dim3(128, 8, 1), thr, 0, stream>>>(x, l1w, l1b, buf2, M, EE, EE, 0, 0, 0, 2);
    // scores[b,c,s] = label_mat[c,:] . o1[b,s,:]  -> attnW  (z = batch)
    gemm_atb<<<dim3(140, 16, 8), thr, 0, stream>>>(label, buf2, nullptr, attnW,
                                                   CC, SS, EE,
                                                   0, (long)SS * EE, (long)CC * SS, 0);
    // softmax over s
    label_softmax<<<BB * CC, 256, 0, stream>>>(attnW);
    // outputs = fc_b, then += sum_s attn * (x . fc_w)
    init_out<<<(BB * CC + 255) / 256, 256, 0, stream>>>(out0, fcb);
    gemm_label_out<<<dim3(140, 16, 8), thr, 0, stream>>>(fcw, x, attnW, out0);
}

// Round 2
// 4873.632 us; speedup vs baseline: 2.0433x; 2.0433x over previous
//
#include <hip/hip_runtime.h>
#include <math.h>

#define BB   8
#define SS   1024
#define EE   512
#define HH   8
#define DHH  64
#define LLY  2
#define CC   8921
#define DFF_ 2048

// ---------------------------------------------------------------------------
// embed: x[b,s,e] = inputs[b,s,e]*sqrt(E) + pe[b,e]   (pe indexed by batch — source bug kept)
// ---------------------------------------------------------------------------
__global__ __launch_bounds__(256) void embed_kernel(const float* __restrict__ in,
                                                    const float* __restrict__ pe,
                                                    float* __restrict__ x)
{
    const long i  = (long)blockIdx.x * 256 + threadIdx.x;   // float4 index over [B,S,E/4]
    const int  e4 = (int)(i & 127);                          // E/4 = 128
    const int  b  = (int)(i >> 17);                          // / (S*E/4) = 131072
    float4 v = ((const float4*)in)[i];
    const float4 p = ((const float4*)pe)[b * 128 + e4];
    const float sc = 22.627416997969522f;                    // sqrt(512)
    v.x = v.x * sc + p.x;  v.y = v.y * sc + p.y;
    v.z = v.z * sc + p.z;  v.w = v.w * sc + p.w;
    ((float4*)x)[i] = v;
}

// ---------------------------------------------------------------------------
// Generic fp32 GEMM: C[m,n] = act( A[m,:] . Bw[n,:] + bias[n] )
// A [M,K] row-major, Bw [N,K] row-major (i.e. C = A @ Bw^T).
// 64x64 tile, K-step 16, 16x16 threads, 4x4 per thread.
// act: 0=none, 1=relu, 2=tanh
// ---------------------------------------------------------------------------
__global__ __launch_bounds__(256) void gemm_atb(const float* __restrict__ A,
                                                const float* __restrict__ Bw,
                                                const float* __restrict__ bias,
                                                float* __restrict__ C,
                                                int M, int N, int K,
                                                long sAz, long sBz, long sCz,
                                                int act)
{
    __shared__ float As[16][64];
    __shared__ float Bs[16][64];
    const int tx = threadIdx.x, ty = threadIdx.y;
    const int tid = ty * 16 + tx;
    const int m0 = blockIdx.x * 64, n0 = blockIdx.y * 64;
    const float* Ab = A  + (long)blockIdx.z * sAz;
    const float* Bb = Bw + (long)blockIdx.z * sBz;
    float*       Cb = C  + (long)blockIdx.z * sCz;

    float acc[4][4] = {};
    const int lr = tid >> 2;          // 0..63
    const int lk = (tid & 3) << 2;    // 0,4,8,12

    for (int k0 = 0; k0 < K; k0 += 16) {
        float4 av = {0.f,0.f,0.f,0.f}, bv = {0.f,0.f,0.f,0.f};
        const int gm = m0 + lr;
        if (gm < M) av = *(const float4*)(Ab + (long)gm * K + k0 + lk);
        const int gn = n0 + lr;
        if (gn < N) bv = *(const float4*)(Bb + (long)gn * K + k0 + lk);
        As[lk + 0][lr] = av.x; As[lk + 1][lr] = av.y;
        As[lk + 2][lr] = av.z; As[lk + 3][lr] = av.w;
        Bs[lk + 0][lr] = bv.x; Bs[lk + 1][lr] = bv.y;
        Bs[lk + 2][lr] = bv.z; Bs[lk + 3][lr] = bv.w;
        __syncthreads();
        #pragma unroll
        for (int kk = 0; kk < 16; ++kk) {
            float a[4], b[4];
            *(float4*)a = *(const float4*)&As[kk][ty << 2];
            *(float4*)b = *(const float4*)&Bs[kk][tx << 2];
            #pragma unroll
            for (int i = 0; i < 4; ++i)
                #pragma unroll
                for (int j = 0; j < 4; ++j)
                    acc[i][j] = fmaf(a[i], b[j], acc[i][j]);
        }
        __syncthreads();
    }

    #pragma unroll
    for (int i = 0; i < 4; ++i) {
        const int gm = m0 + (ty << 2) + i;
        if (gm >= M) continue;
        #pragma unroll
        for (int j = 0; j < 4; ++j) {
            const int gn = n0 + (tx << 2) + j;
            if (gn >= N) continue;
            float v = acc[i][j];
            if (bias) v += bias[gn];
            if (act == 1)      v = fmaxf(v, 0.f);
            else if (act == 2) v = tanhf(v);
            Cb[(long)gm * N + gn] = v;
        }
    }
}

// ---------------------------------------------------------------------------
// Flash-style fp32 self-attention. One block per (b,h,64 q-rows).
// Q,K,V from qkv [B,S,3E]; K/V tiles staged in LDS; scores in registers;
// online softmax; PV from LDS. 1/sqrt(DH) folded into Q load.
// Thread map (16x16): thread owns q rows ty*4+i; score cols tx*4+j (s),
// output cols tx*4+j (d).
// ---------------------------------------------------------------------------
__global__ __launch_bounds__(256) void flash_attn(const float* __restrict__ qkv,
                                                  float* __restrict__ o)
{
    const int bh = blockIdx.y;
    const int b  = bh >> 3, h = bh & 7;
    const int q0 = blockIdx.x << 6;

    __shared__ float sQ[64][68];
    __shared__ float sA[64][68];   // K tile, then P tile
    __shared__ float sV[64][68];

    const int t  = threadIdx.x;
    const int tx = t & 15, ty = t >> 4;

    const long  base  = (long)b * SS * (3 * EE);
    const float* qbase = qkv + base + h * DHH;
    const float* kbase = qkv + base + EE + h * DHH;
    const float* vbase = qkv + base + 2 * EE + h * DHH;

    // load Q tile (scaled by 1/8)
    {
        const int row = t >> 4;          // 0..15
        const int c4  = (t & 15) << 2;   // 0..60
        #pragma unroll
        for (int rr = 0; rr < 64; rr += 16) {
            float4 q = *(const float4*)(qbase + (long)(q0 + row + rr) * (3 * EE) + c4);
            q.x *= 0.125f; q.y *= 0.125f; q.z *= 0.125f; q.w *= 0.125f;
            *(float4*)&sQ[row + rr][c4] = q;
        }
    }

    float m_r[4], l_r[4], accO[4][4];
    #pragma unroll
    for (int i = 0; i < 4; ++i) {
        m_r[i] = -1e30f; l_r[i] = 0.f;
        #pragma unroll
        for (int j = 0; j < 4; ++j) accO[i][j] = 0.f;
    }

    for (int s0 = 0; s0 < SS; s0 += 64) {
        __syncthreads();   // covers Q-load (iter 0) and prev-iter P/V reads
        {
            const int row = t >> 4;
            const int c4  = (t & 15) << 2;
            #pragma unroll
            for (int rr = 0; rr < 64; rr += 16) {
                *(float4*)&sA[row + rr][c4] =
                    *(const float4*)(kbase + (long)(s0 + row + rr) * (3 * EE) + c4);
                *(float4*)&sV[row + rr][c4] =
                    *(const float4*)(vbase + (long)(s0 + row + rr) * (3 * EE) + c4);
            }
        }
        __syncthreads();

        // scores: sc[i][j] = (Q/8)[q0+ty*4+i] . K[s0+tx*4+j]
        float sc[4][4] = {};
        #pragma unroll
        for (int d = 0; d < DHH; d += 4) {
            float4 qv[4], kv[4];
            #pragma unroll
            for (int i = 0; i < 4; ++i) qv[i] = *(const float4*)&sQ[(ty << 2) + i][d];
            #pragma unroll
            for (int j = 0; j < 4; ++j) kv[j] = *(const float4*)&sA[(tx << 2) + j][d];
            #pragma unroll
            for (int i = 0; i < 4; ++i)
                #pragma unroll
                for (int j = 0; j < 4; ++j)
                    sc[i][j] = fmaf(qv[i].x, kv[j].x, fmaf(qv[i].y, kv[j].y,
                               fmaf(qv[i].z, kv[j].z, fmaf(qv[i].w, kv[j].w, sc[i][j]))));
        }

        // online softmax update (per q row i; reduce across tx lanes)
        #pragma unroll
        for (int i = 0; i < 4; ++i) {
            float mx = fmaxf(fmaxf(sc[i][0], sc[i][1]), fmaxf(sc[i][2], sc[i][3]));
            #pragma unroll
            for (int off = 1; off < 16; off <<= 1) mx = fmaxf(mx, __shfl_xor(mx, off));
            const float mnew = fmaxf(m_r[i], mx);
            const float f = __expf(m_r[i] - mnew);
            m_r[i] = mnew;
            float s = 0.f;
            #pragma unroll
            for (int j = 0; j < 4; ++j) { sc[i][j] = __expf(sc[i][j] - mnew); s += sc[i][j]; }
            #pragma unroll
            for (int off = 1; off < 16; off <<= 1) s += __shfl_xor(s, off);
            l_r[i] = l_r[i] * f + s;
            #pragma unroll
            for (int j = 0; j < 4; ++j) accO[i][j] *= f;
        }

        __syncthreads();   // all K reads done -> sA reusable for P
        #pragma unroll
        for (int i = 0; i < 4; ++i)
            *(float4*)&sA[(ty << 2) + i][tx << 2] = *(float4*)&sc[i][0];
        __syncthreads();

        // accO[i][j] += sum_s P[q][s] * V[s][d]
        #pragma unroll 4
        for (int s = 0; s < 64; ++s) {
            const float4 vv = *(const float4*)&sV[s][tx << 2];
            #pragma unroll
            for (int i = 0; i < 4; ++i) {
                const float p = sA[(ty << 2) + i][s];
                accO[i][0] = fmaf(p, vv.x, accO[i][0]);
                accO[i][1] = fmaf(p, vv.y, accO[i][1]);
                accO[i][2] = fmaf(p, vv.z, accO[i][2]);
                accO[i][3] = fmaf(p, vv.w, accO[i][3]);
            }
        }
    }

    #pragma unroll
    for (int i = 0; i < 4; ++i) {
        const float iv = 1.f / l_r[i];
        float4 r = { accO[i][0] * iv, accO[i][1] * iv, accO[i][2] * iv, accO[i][3] * iv };
        *(float4*)(o + (long)(b * SS + q0 + (ty << 2) + i) * EE + h * DHH + (tx << 2)) = r;
    }
}

// ---------------------------------------------------------------------------
// Fused residual + LayerNorm, in place:  x = LN(x + o) * g + b   (row = B*S, E=512)
// ---------------------------------------------------------------------------
__global__ __launch_bounds__(256) void ln_fused(float* __restrict__ x,
                                                const float* __restrict__ o,
                                                const float* __restrict__ g,
                                                const float* __restrict__ bta)
{
    const long row = blockIdx.x;
    float* xr = x + row * EE;
    const float* orr = o + row * EE;
    const int t = threadIdx.x;
    const float v0 = xr[t] + orr[t];
    const float v1 = xr[t + 256] + orr[t + 256];
    float s = v0 + v1;
    #pragma unroll
    for (int off = 1; off < 64; off <<= 1) s += __shfl_xor(s, off);
    __shared__ float r1[4], r2[4];
    if ((t & 63) == 0) r1[t >> 6] = s;
    __syncthreads();
    const float mu = (r1[0] + r1[1] + r1[2] + r1[3]) * (1.f / EE);
    const float d0 = v0 - mu, d1 = v1 - mu;
    float q = d0 * d0 + d1 * d1;
    #pragma unroll
    for (int off = 1; off < 64; off <<= 1) q += __shfl_xor(q, off);
    if ((t & 63) == 0) r2[t >> 6] = q;
    __syncthreads();
    const float rs = rsqrtf((r2[0] + r2[1] + r2[2] + r2[3]) * (1.f / EE) + 1e-5f);
    xr[t]       = d0 * rs * g[t]       + bta[t];
    xr[t + 256] = d1 * rs * g[t + 256] + bta[t + 256];
}

// ---------------------------------------------------------------------------
// Label softmax over seq dim: attn[b,c,:] = softmax(attn[b,c,:]), rows = B*C, S=1024
// ---------------------------------------------------------------------------
__global__ __launch_bounds__(256) void label_softmax(float* __restrict__ attn)
{
    const long row = blockIdx.x;
    float* p = attn + row * (long)SS;
    const int t = threadIdx.x;
    float4 v = ((float4*)p)[t];
    __shared__ float red[4];
    float mx = fmaxf(fmaxf(v.x, v.y), fmaxf(v.z, v.w));
    #pragma unroll
    for (int off = 1; off < 64; off <<= 1) mx = fmaxf(mx, __shfl_xor(mx, off));
    if ((t & 63) == 0) red[t >> 6] = mx;
    __syncthreads();
    mx = fmaxf(fmaxf(red[0], red[1]), fmaxf(red[2], red[3]));
    v.x = __expf(v.x - mx); v.y = __expf(v.y - mx);
    v.z = __expf(v.z - mx); v.w = __expf(v.w - mx);
    float s = v.x + v.y + v.z + v.w;
    #pragma unroll
    for (int off = 1; off < 64; off <<= 1) s += __shfl_xor(s, off);
    __syncthreads();
    if ((t & 63) == 0) red[t >> 6] = s;
    __syncthreads();
    const float inv = 1.f / (red[0] + red[1] + red[2] + red[3]);
    v.x *= inv; v.y *= inv; v.z *= inv; v.w *= inv;
    ((float4*)p)[t] = v;
}

// ---------------------------------------------------------------------------
// outputs init: out[b,c] = fc_b[c]
// ---------------------------------------------------------------------------
__global__ __launch_bounds__(256) void init_out(float* __restrict__ out,
                                                const float* __restrict__ fcb)
{
    const int i = blockIdx.x * 256 + threadIdx.x;
    if (i < BB * CC) out[i] = fcb[i % CC];
}

// ---------------------------------------------------------------------------
// Fused label-output GEMM:
//   D[c,s] = fc_w[c,:] . x[b,s,:]
//   out[b,c] += sum_s attn[b,c,s] * D[c,s]
// ---------------------------------------------------------------------------
__global__ __launch_bounds__(256) void gemm_label_out(const float* __restrict__ A,    // fc_w [C,E]
                                                      const float* __restrict__ Bx,   // x [B,S,E]
                                                      const float* __restrict__ attn, // [B,C,S]
                                                      float* __restrict__ out)        // [B,C]
{
    __shared__ float As[16][64];
    __shared__ float Bs[16][64];
    const int tx = threadIdx.x, ty = threadIdx.y;
    const int tid = ty * 16 + tx;
    const int m0 = blockIdx.x * 64, n0 = blockIdx.y * 64;
    const int b = blockIdx.z;
    const float* Bb   = Bx   + (long)b * SS * EE;
    const float* attb = attn + (long)b * CC * SS;
    float*       outb = out  + (long)b * CC;

    float acc[4][4] = {};
    const int lr = tid >> 2;
    const int lk = (tid & 3) << 2;

    for (int k0 = 0; k0 < EE; k0 += 16) {
        float4 av = {0.f,0.f,0.f,0.f};
        const int gm = m0 + lr;
        if (gm < CC) av = *(const float4*)(A + (long)gm * EE + k0 + lk);
        const float4 bv = *(const float4*)(Bb + (long)(n0 + lr) * EE + k0 + lk);
        As[lk + 0][lr] = av.x; As[lk + 1][lr] = av.y;
        As[lk + 2][lr] = av.z; As[lk + 3][lr] = av.w;
        Bs[lk + 0][lr] = bv.x; Bs[lk + 1][lr] = bv.y;
        Bs[lk + 2][lr] = bv.z; Bs[lk + 3][lr] = bv.w;
        __syncthreads();
        #pragma unroll
        for (int kk = 0; kk < 16; ++kk) {
            float a[4], bcol[4];
            *(float4*)a    = *(const float4*)&As[kk][ty << 2];
            *(float4*)bcol = *(const float4*)&Bs[kk][tx << 2];
            #pragma unroll
            for (int i = 0; i < 4; ++i)
                #pragma unroll
                for (int j = 0; j < 4; ++j)
                    acc[i][j] = fmaf(a[i], bcol[j], acc[i][j]);
        }
        __syncthreads();
    }

    float part[4];
    #pragma unroll
    for (int i = 0; i < 4; ++i) {
        const int c = m0 + (ty << 2) + i;
        float p = 0.f;
        if (c < CC) {
            const float4 aw = *(const float4*)(attb + (long)c * SS + n0 + (tx << 2));
            p = acc[i][0] * aw.x + acc[i][1] * aw.y + acc[i][2] * aw.z + acc[i][3] * aw.w;
        }
        #pragma unroll
        for (int off = 1; off < 16; off <<= 1) p += __shfl_xor(p, off);
        part[i] = p;
    }
    if (tx == 0) {
        #pragma unroll
        for (int i = 0; i < 4; ++i) {
            const int c = m0 + (ty << 2) + i;
            if (c < CC) atomicAdd(&outb[c], part[i]);
        }
    }
}

// ---------------------------------------------------------------------------
extern "C" void kernel_launch(void* const* d_in, const int* in_sizes, int n_in,
                              void* d_out, int out_size, void* d_ws, size_t ws_size,
                              hipStream_t stream)
{
    const float* inp   = (const float*)d_in[0];
    const float* pe    = (const float*)d_in[1];
    const float* label = (const float*)d_in[2];
    const float* l1w   = (const float*)d_in[3];
    const float* l1b   = (const float*)d_in[4];
    const float* fcw   = (const float*)d_in[5];
    const float* fcb   = (const float*)d_in[6];
    const float* ipw   = (const float*)d_in[7];
    const float* ipb   = (const float*)d_in[8];
    const float* opw   = (const float*)d_in[9];
    const float* opb   = (const float*)d_in[10];
    const float* g1    = (const float*)d_in[11];
    const float* b1    = (const float*)d_in[12];
    const float* g2    = (const float*)d_in[13];
    const float* b2    = (const float*)d_in[14];
    const float* w1    = (const float*)d_in[15];
    const float* bb1   = (const float*)d_in[16];
    const float* w2    = (const float*)d_in[17];
    const float* bb2   = (const float*)d_in[18];

    float* x    = (float*)d_ws;                       // [B,S,E]
    float* buf1 = x + (long)BB * SS * EE;             // [B,S,3E] / [B,S,DFF]
    float* buf2 = buf1 + (long)BB * SS * DFF_;        // [B,S,E]

    float* out0  = (float*)d_out;                     // [B,C]
    float* attnW = out0 + BB * CC;                    // [B,C,S]

    const dim3 thr(16, 16);
    const int M = BB * SS;                            // 8192

    embed_kernel<<<4096, 256, 0, stream>>>(inp, pe, x);

    for (int l = 0; l < LLY; ++l) {
        gemm_atb<<<dim3(128, 24, 1), thr, 0, stream>>>(x, ipw + (long)l * 3 * EE * EE,
                                                       ipb + l * 3 * EE, buf1,
                                                       M, 3 * EE, EE, 0, 0, 0, 0);
        flash_attn<<<dim3(16, 64), 256, 0, stream>>>(buf1, buf2);
        gemm_atb<<<dim3(128, 8, 1), thr, 0, stream>>>(buf2, opw + (long)l * EE * EE,
                                                      opb + l * EE, buf1,
                                                      M, EE, EE, 0, 0, 0, 0);
        ln_fused<<<M, 256, 0, stream>>>(x, buf1, g1 + l * EE, b1 + l * EE);
        gemm_atb<<<dim3(128, 32, 1), thr, 0, stream>>>(x, w1 + (long)l * DFF_ * EE,
                                                       bb1 + l * DFF_, buf1,
                                                       M, DFF_, EE, 0, 0, 0, 1);
        gemm_atb<<<dim3(128, 8, 1), thr, 0, stream>>>(buf1, w2 + (long)l * EE * DFF_,
                                                      bb2 + l * EE, buf2,
                                                      M, EE, DFF_, 0, 0, 0, 0);
        ln_fused<<<M, 256, 0, stream>>>(x, buf2, g2 + l * EE, b2 + l * EE);
    }

    gemm_atb<<<dim3(128, 8, 1), thr, 0, stream>>>(x, l1w, l1b, buf2, M, EE, EE, 0, 0, 0, 2);
    gemm_atb<<<dim3(140, 16, 8), thr, 0, stream>>>(label, buf2, nullptr, attnW,
                                                   CC, SS, EE,
                                                   0, (long)SS * EE, (long)CC * SS, 0);
    label_softmax<<<BB * CC, 256, 0, stream>>>(attnW);
    init_out<<<(BB * CC + 255) / 256, 256, 0, stream>>>(out0, fcb);
    gemm_label_out<<<dim3(140, 16, 8), thr, 0, stream>>>(fcw, x, attnW, out0);
}

// Round 3
// 1616.559 us; speedup vs baseline: 6.1602x; 3.0148x over previous
//
#include <hip/hip_runtime.h>
#include <math.h>

#define BB   8
#define SS   1024
#define EE   512
#define HH   8
#define DHH  64
#define LLY  2
#define CC   8921
#define CP   9088          // C padded to multiple of 128
#define DFF_ 2048

typedef short          bf16x8 __attribute__((ext_vector_type(8)));
typedef float          f32x4  __attribute__((ext_vector_type(4)));
typedef unsigned short u16x4  __attribute__((ext_vector_type(4)));
typedef unsigned short u16x8  __attribute__((ext_vector_type(8)));

__device__ __forceinline__ float bf2f(unsigned short u) {
    return __uint_as_float(((unsigned int)u) << 16);
}
__device__ __forceinline__ unsigned short f2bf(float f) {
    unsigned int u = __float_as_uint(f);
    u = (u + 0x7FFFu + ((u >> 16) & 1u)) >> 16;
    return (unsigned short)u;
}
__device__ __forceinline__ void gload16(const void* g, void* l) {
    __builtin_amdgcn_global_load_lds(
        (const __attribute__((address_space(1))) void*)g,
        (__attribute__((address_space(3))) void*)l, 16, 0, 0);
}

// ---------------------------------------------------------------------------
// f32 -> bf16 convert with zero-pad (row padding is whole 4-element groups)
// ---------------------------------------------------------------------------
__global__ __launch_bounds__(256) void cvt_bf16(const float* __restrict__ in,
                                                unsigned short* __restrict__ out,
                                                long n_in, long n_out)
{
    const long i4 = ((long)blockIdx.x * 256 + threadIdx.x) * 4;
    if (i4 >= n_out) return;
    u16x4 r;
    if (i4 < n_in) {
        const float4 v = *(const float4*)(in + i4);
        r[0] = f2bf(v.x); r[1] = f2bf(v.y); r[2] = f2bf(v.z); r[3] = f2bf(v.w);
    } else {
        r[0] = r[1] = r[2] = r[3] = 0;
    }
    *(u16x4*)(out + i4) = r;
}

// ---------------------------------------------------------------------------
// embed: x = inputs*sqrt(E) + pe[b]  (pe indexed by batch — source bug kept)
// writes f32 x and bf16 xb
// ---------------------------------------------------------------------------
__global__ __launch_bounds__(256) void embed_kernel(const float* __restrict__ in,
                                                    const float* __restrict__ pe,
                                                    float* __restrict__ x,
                                                    unsigned short* __restrict__ xb)
{
    const long i  = (long)blockIdx.x * 256 + threadIdx.x;   // float4 index
    const int  e4 = (int)(i & 127);
    const int  b  = (int)(i >> 17);
    float4 v = ((const float4*)in)[i];
    const float4 p = ((const float4*)pe)[b * 128 + e4];
    const float sc = 22.627416997969522f;
    v.x = v.x * sc + p.x;  v.y = v.y * sc + p.y;
    v.z = v.z * sc + p.z;  v.w = v.w * sc + p.w;
    ((float4*)x)[i] = v;
    u16x4 h; h[0] = f2bf(v.x); h[1] = f2bf(v.y); h[2] = f2bf(v.z); h[3] = f2bf(v.w);
    ((u16x4*)xb)[i] = h;
}

// ---------------------------------------------------------------------------
// bf16 MFMA GEMM: C[m,n] = act( A[m,:].B[n,:] + bias[n] )
// A [M,K] bf16 row-major, B [N,K] bf16 row-major. 128x128 tile, BK=64.
// 4 waves (2x2), each 64x64 via 4x4 frags of mfma_f32_16x16x32_bf16.
// Staging: global_load_lds w=16 into linear LDS, source pre-swizzled
// (u = (l&7)^(l>>3)); reads XOR-swizzled (slot ^= row&7)  -> ~2-way conflicts.
// mode bit0: f32 out to Cf; bit1: bf16 out to Ch. act 0=none 1=relu 2=tanh.
// ---------------------------------------------------------------------------
__global__ __launch_bounds__(256) void gemm_mfma(const unsigned short* __restrict__ A,
                                                 const unsigned short* __restrict__ B,
                                                 const float* __restrict__ bias,
                                                 float* __restrict__ Cf,
                                                 unsigned short* __restrict__ Ch,
                                                 int M, int N, int K, int Mlim,
                                                 long sAz, long sBz, long sCz,
                                                 int act, int mode)
{
    __shared__ unsigned short As[128 * 64];
    __shared__ unsigned short Bs[128 * 64];
    const int t  = threadIdx.x;
    const int wv = t >> 6, ln = t & 63;
    const int wr = wv >> 1, wc = wv & 1;
    const int lr = ln & 15, lg = ln >> 4;
    const int m0 = blockIdx.x * 128, n0 = blockIdx.y * 128;
    const int z  = blockIdx.z;
    const unsigned short* Ab = A + (long)z * sAz;
    const unsigned short* Bb = B + (long)z * sBz;

    const int srow = ln >> 3;                       // row within 8-row chunk
    const int ucol = ((ln & 7) ^ srow) << 3;        // inverse-swizzled src col

    f32x4 acc[4][4];
    #pragma unroll
    for (int i = 0; i < 4; ++i)
        #pragma unroll
        for (int j = 0; j < 4; ++j)
            acc[i][j] = (f32x4){0.f, 0.f, 0.f, 0.f};

    int rA[4], rB[4];
    #pragma unroll
    for (int f = 0; f < 4; ++f) {
        rA[f] = wr * 64 + f * 16 + lr;
        rB[f] = wc * 64 + f * 16 + lr;
    }

    for (int k0 = 0; k0 < K; k0 += 64) {
        __syncthreads();
        #pragma unroll
        for (int c = 0; c < 4; ++c) {
            const int q   = (wv << 2) + c;
            const int row = (q << 3) + srow;
            gload16(Ab + (long)(m0 + row) * K + k0 + ucol, (char*)As + (q << 10));
            gload16(Bb + (long)(n0 + row) * K + k0 + ucol, (char*)Bs + (q << 10));
        }
        __syncthreads();
        #pragma unroll
        for (int kk = 0; kk < 2; ++kk) {
            bf16x8 af[4], bg[4];
            const int s = (kk << 2) + lg;
            #pragma unroll
            for (int f = 0; f < 4; ++f) {
                af[f] = *(const bf16x8*)((const char*)As + rA[f] * 128 + ((s ^ (rA[f] & 7)) << 4));
                bg[f] = *(const bf16x8*)((const char*)Bs + rB[f] * 128 + ((s ^ (rB[f] & 7)) << 4));
            }
            #pragma unroll
            for (int i = 0; i < 4; ++i)
                #pragma unroll
                for (int j = 0; j < 4; ++j)
                    acc[i][j] = __builtin_amdgcn_mfma_f32_16x16x32_bf16(af[i], bg[j], acc[i][j], 0, 0, 0);
        }
    }

    const long zC = (long)z * sCz;
    #pragma unroll
    for (int fm = 0; fm < 4; ++fm) {
        #pragma unroll
        for (int reg = 0; reg < 4; ++reg) {
            const int gm = m0 + wr * 64 + fm * 16 + lg * 4 + reg;
            if (gm >= Mlim) continue;
            #pragma unroll
            for (int fn = 0; fn < 4; ++fn) {
                const int gn = n0 + wc * 64 + fn * 16 + lr;
                float v = acc[fm][fn][reg];
                if (bias) v += bias[gn];
                if (act == 1)      v = fmaxf(v, 0.f);
                else if (act == 2) v = tanhf(v);
                if (mode & 1) Cf[zC + (long)gm * N + gn] = v;
                if (mode & 2) Ch[zC + (long)gm * N + gn] = f2bf(v);
            }
        }
    }
}

// ---------------------------------------------------------------------------
// Fused label-output GEMM (MFMA):
//   D[c,s] = fcw[c,:].x[b,s,:];  out[b,c] += sum_s attn[b,c,s]*D[c,s]
// ---------------------------------------------------------------------------
__global__ __launch_bounds__(256) void gemm_label_mfma(const unsigned short* __restrict__ A,   // fcw_b [CP,E]
                                                       const unsigned short* __restrict__ B,   // xb [B*S,E]
                                                       const float* __restrict__ attn,         // [B,C,S]
                                                       float* __restrict__ out)                // [B,C]
{
    __shared__ unsigned short As[128 * 64];
    __shared__ unsigned short Bs[128 * 64];
    const int t  = threadIdx.x;
    const int wv = t >> 6, ln = t & 63;
    const int wr = wv >> 1, wc = wv & 1;
    const int lr = ln & 15, lg = ln >> 4;
    const int m0 = blockIdx.x * 128, n0 = blockIdx.y * 128;
    const int z  = blockIdx.z;
    const unsigned short* Bb = B + (long)z * SS * EE;

    const int srow = ln >> 3;
    const int ucol = ((ln & 7) ^ srow) << 3;

    f32x4 acc[4][4];
    #pragma unroll
    for (int i = 0; i < 4; ++i)
        #pragma unroll
        for (int j = 0; j < 4; ++j)
            acc[i][j] = (f32x4){0.f, 0.f, 0.f, 0.f};

    int rA[4], rB[4];
    #pragma unroll
    for (int f = 0; f < 4; ++f) {
        rA[f] = wr * 64 + f * 16 + lr;
        rB[f] = wc * 64 + f * 16 + lr;
    }

    for (int k0 = 0; k0 < EE; k0 += 64) {
        __syncthreads();
        #pragma unroll
        for (int c = 0; c < 4; ++c) {
            const int q   = (wv << 2) + c;
            const int row = (q << 3) + srow;
            gload16(A  + (long)(m0 + row) * EE + k0 + ucol, (char*)As + (q << 10));
            gload16(Bb + (long)(n0 + row) * EE + k0 + ucol, (char*)Bs + (q << 10));
        }
        __syncthreads();
        #pragma unroll
        for (int kk = 0; kk < 2; ++kk) {
            bf16x8 af[4], bg[4];
            const int s = (kk << 2) + lg;
            #pragma unroll
            for (int f = 0; f < 4; ++f) {
                af[f] = *(const bf16x8*)((const char*)As + rA[f] * 128 + ((s ^ (rA[f] & 7)) << 4));
                bg[f] = *(const bf16x8*)((const char*)Bs + rB[f] * 128 + ((s ^ (rB[f] & 7)) << 4));
            }
            #pragma unroll
            for (int i = 0; i < 4; ++i)
                #pragma unroll
                for (int j = 0; j < 4; ++j)
                    acc[i][j] = __builtin_amdgcn_mfma_f32_16x16x32_bf16(af[i], bg[j], acc[i][j], 0, 0, 0);
        }
    }

    const float* attb = attn + (long)z * CC * SS;
    float*       outb = out  + (long)z * CC;
    #pragma unroll
    for (int fm = 0; fm < 4; ++fm) {
        #pragma unroll
        for (int reg = 0; reg < 4; ++reg) {
            const int r = m0 + wr * 64 + fm * 16 + lg * 4 + reg;
            float p = 0.f;
            if (r < CC) {
                #pragma unroll
                for (int fn = 0; fn < 4; ++fn) {
                    const int sn = n0 + wc * 64 + fn * 16 + lr;
                    p += acc[fm][fn][reg] * attb[(long)r * SS + sn];
                }
            }
            p += __shfl_xor(p, 1);
            p += __shfl_xor(p, 2);
            p += __shfl_xor(p, 4);
            p += __shfl_xor(p, 8);
            if (lr == 0 && r < CC) atomicAdd(&outb[r], p);
        }
    }
}

// ---------------------------------------------------------------------------
// Flash-style self-attention, bf16 qkv in, bf16 o out. Block = (b,h,64 q rows).
// ---------------------------------------------------------------------------
__global__ __launch_bounds__(256) void flash_attn(const unsigned short* __restrict__ qkv,
                                                  unsigned short* __restrict__ o)
{
    const int bh = blockIdx.y;
    const int b  = bh >> 3, h = bh & 7;
    const int q0 = blockIdx.x << 6;

    __shared__ float sQ[64][68];
    __shared__ float sA[64][68];   // K tile, then P tile
    __shared__ float sV[64][68];

    const int t  = threadIdx.x;
    const int tx = t & 15, ty = t >> 4;

    const unsigned short* qbase = qkv + (long)b * SS * (3 * EE) + h * DHH;
    const unsigned short* kbase = qbase + EE;
    const unsigned short* vbase = qbase + 2 * EE;

    {   // Q tile, scaled by 1/8
        const int r  = t >> 3;          // 0..31
        const int c8 = (t & 7) << 3;
        #pragma unroll
        for (int rr = 0; rr < 64; rr += 32) {
            const u16x8 v = *(const u16x8*)(qbase + (long)(q0 + r + rr) * (3 * EE) + c8);
            #pragma unroll
            for (int j = 0; j < 8; ++j) sQ[r + rr][c8 + j] = bf2f(v[j]) * 0.125f;
        }
    }

    float m_r[4], l_r[4], accO[4][4];
    #pragma unroll
    for (int i = 0; i < 4; ++i) {
        m_r[i] = -1e30f; l_r[i] = 0.f;
        #pragma unroll
        for (int j = 0; j < 4; ++j) accO[i][j] = 0.f;
    }

    for (int s0 = 0; s0 < SS; s0 += 64) {
        __syncthreads();
        {
            const int r  = t >> 3;
            const int c8 = (t & 7) << 3;
            #pragma unroll
            for (int rr = 0; rr < 64; rr += 32) {
                const u16x8 kv = *(const u16x8*)(kbase + (long)(s0 + r + rr) * (3 * EE) + c8);
                const u16x8 vv = *(const u16x8*)(vbase + (long)(s0 + r + rr) * (3 * EE) + c8);
                #pragma unroll
                for (int j = 0; j < 8; ++j) {
                    sA[r + rr][c8 + j] = bf2f(kv[j]);
                    sV[r + rr][c8 + j] = bf2f(vv[j]);
                }
            }
        }
        __syncthreads();

        float sc[4][4] = {};
        #pragma unroll
        for (int d = 0; d < DHH; d += 4) {
            float4 qv[4], kv[4];
            #pragma unroll
            for (int i = 0; i < 4; ++i) qv[i] = *(const float4*)&sQ[(ty << 2) + i][d];
            #pragma unroll
            for (int j = 0; j < 4; ++j) kv[j] = *(const float4*)&sA[(tx << 2) + j][d];
            #pragma unroll
            for (int i = 0; i < 4; ++i)
                #pragma unroll
                for (int j = 0; j < 4; ++j)
                    sc[i][j] = fmaf(qv[i].x, kv[j].x, fmaf(qv[i].y, kv[j].y,
                               fmaf(qv[i].z, kv[j].z, fmaf(qv[i].w, kv[j].w, sc[i][j]))));
        }

        #pragma unroll
        for (int i = 0; i < 4; ++i) {
            float mx = fmaxf(fmaxf(sc[i][0], sc[i][1]), fmaxf(sc[i][2], sc[i][3]));
            #pragma unroll
            for (int off = 1; off < 16; off <<= 1) mx = fmaxf(mx, __shfl_xor(mx, off));
            const float mnew = fmaxf(m_r[i], mx);
            const float f = __expf(m_r[i] - mnew);
            m_r[i] = mnew;
            float s = 0.f;
            #pragma unroll
            for (int j = 0; j < 4; ++j) { sc[i][j] = __expf(sc[i][j] - mnew); s += sc[i][j]; }
            #pragma unroll
            for (int off = 1; off < 16; off <<= 1) s += __shfl_xor(s, off);
            l_r[i] = l_r[i] * f + s;
            #pragma unroll
            for (int j = 0; j < 4; ++j) accO[i][j] *= f;
        }

        __syncthreads();
        #pragma unroll
        for (int i = 0; i < 4; ++i)
            *(float4*)&sA[(ty << 2) + i][tx << 2] = *(float4*)&sc[i][0];
        __syncthreads();

        #pragma unroll 4
        for (int s = 0; s < 64; ++s) {
            const float4 vv = *(const float4*)&sV[s][tx << 2];
            #pragma unroll
            for (int i = 0; i < 4; ++i) {
                const float p = sA[(ty << 2) + i][s];
                accO[i][0] = fmaf(p, vv.x, accO[i][0]);
                accO[i][1] = fmaf(p, vv.y, accO[i][1]);
                accO[i][2] = fmaf(p, vv.z, accO[i][2]);
                accO[i][3] = fmaf(p, vv.w, accO[i][3]);
            }
        }
    }

    #pragma unroll
    for (int i = 0; i < 4; ++i) {
        const float iv = 1.f / l_r[i];
        u16x4 r;
        r[0] = f2bf(accO[i][0] * iv); r[1] = f2bf(accO[i][1] * iv);
        r[2] = f2bf(accO[i][2] * iv); r[3] = f2bf(accO[i][3] * iv);
        *(u16x4*)(o + (long)(b * SS + q0 + (ty << 2) + i) * EE + h * DHH + (tx << 2)) = r;
    }
}

// ---------------------------------------------------------------------------
// Fused residual + LayerNorm, in place; also writes bf16 copy.
// ---------------------------------------------------------------------------
__global__ __launch_bounds__(256) void ln_fused(float* __restrict__ x,
                                                unsigned short* __restrict__ xb,
                                                const float* __restrict__ o,
                                                const float* __restrict__ g,
                                                const float* __restrict__ bta)
{
    const long row = blockIdx.x;
    float* xr = x + row * EE;
    unsigned short* hb = xb + row * EE;
    const float* orr = o + row * EE;
    const int t = threadIdx.x;
    const float v0 = xr[t] + orr[t];
    const float v1 = xr[t + 256] + orr[t + 256];
    float s = v0 + v1;
    #pragma unroll
    for (int off = 1; off < 64; off <<= 1) s += __shfl_xor(s, off);
    __shared__ float r1[4], r2[4];
    if ((t & 63) == 0) r1[t >> 6] = s;
    __syncthreads();
    const float mu = (r1[0] + r1[1] + r1[2] + r1[3]) * (1.f / EE);
    const float d0 = v0 - mu, d1 = v1 - mu;
    float q = d0 * d0 + d1 * d1;
    #pragma unroll
    for (int off = 1; off < 64; off <<= 1) q += __shfl_xor(q, off);
    if ((t & 63) == 0) r2[t >> 6] = q;
    __syncthreads();
    const float rs = rsqrtf((r2[0] + r2[1] + r2[2] + r2[3]) * (1.f / EE) + 1e-5f);
    const float y0 = d0 * rs * g[t]       + bta[t];
    const float y1 = d1 * rs * g[t + 256] + bta[t + 256];
    xr[t] = y0;  xr[t + 256] = y1;
    hb[t] = f2bf(y0);  hb[t + 256] = f2bf(y1);
}

// ---------------------------------------------------------------------------
// Label softmax over seq dim: rows = B*C, S=1024
// ---------------------------------------------------------------------------
__global__ __launch_bounds__(256) void label_softmax(float* __restrict__ attn)
{
    const long row = blockIdx.x;
    float* p = attn + row * (long)SS;
    const int t = threadIdx.x;
    float4 v = ((float4*)p)[t];
    __shared__ float red[4];
    float mx = fmaxf(fmaxf(v.x, v.y), fmaxf(v.z, v.w));
    #pragma unroll
    for (int off = 1; off < 64; off <<= 1) mx = fmaxf(mx, __shfl_xor(mx, off));
    if ((t & 63) == 0) red[t >> 6] = mx;
    __syncthreads();
    mx = fmaxf(fmaxf(red[0], red[1]), fmaxf(red[2], red[3]));
    v.x = __expf(v.x - mx); v.y = __expf(v.y - mx);
    v.z = __expf(v.z - mx); v.w = __expf(v.w - mx);
    float s = v.x + v.y + v.z + v.w;
    #pragma unroll
    for (int off = 1; off < 64; off <<= 1) s += __shfl_xor(s, off);
    __syncthreads();
    if ((t & 63) == 0) red[t >> 6] = s;
    __syncthreads();
    const float inv = 1.f / (red[0] + red[1] + red[2] + red[3]);
    v.x *= inv; v.y *= inv; v.z *= inv; v.w *= inv;
    ((float4*)p)[t] = v;
}

__global__ __launch_bounds__(256) void init_out(float* __restrict__ out,
                                                const float* __restrict__ fcb)
{
    const int i = blockIdx.x * 256 + threadIdx.x;
    if (i < BB * CC) out[i] = fcb[i % CC];
}

// ---------------------------------------------------------------------------
extern "C" void kernel_launch(void* const* d_in, const int* in_sizes, int n_in,
                              void* d_out, int out_size, void* d_ws, size_t ws_size,
                              hipStream_t stream)
{
    const float* inp   = (const float*)d_in[0];
    const float* pe    = (const float*)d_in[1];
    const float* label = (const float*)d_in[2];
    const float* l1w   = (const float*)d_in[3];
    const float* l1b   = (const float*)d_in[4];
    const float* fcw   = (const float*)d_in[5];
    const float* fcb   = (const float*)d_in[6];
    const float* ipw   = (const float*)d_in[7];
    const float* ipb   = (const float*)d_in[8];
    const float* opw   = (const float*)d_in[9];
    const float* opb   = (const float*)d_in[10];
    const float* g1    = (const float*)d_in[11];
    const float* b1    = (const float*)d_in[12];
    const float* g2    = (const float*)d_in[13];
    const float* b2    = (const float*)d_in[14];
    const float* w1    = (const float*)d_in[15];
    const float* bb1   = (const float*)d_in[16];
    const float* w2    = (const float*)d_in[17];
    const float* bb2   = (const float*)d_in[18];

    // ---- workspace layout -------------------------------------------------
    char* wp = (char*)d_ws;
    float* x = (float*)wp;                 wp += (long)BB * SS * EE * 4;      // f32 activations
    unsigned short* xb = (unsigned short*)wp;  wp += (long)BB * SS * EE * 2;  // bf16 activations
    float* bufo = (float*)wp;              wp += (long)BB * SS * EE * 4;      // f32 gemm out (proj/ff2)
    unsigned short* big = (unsigned short*)wp; wp += (long)BB * SS * DFF_ * 2;// qkvb / ff1b (time-shared)
    unsigned short* ob  = (unsigned short*)wp; wp += (long)BB * SS * EE * 2;  // attn-out / o1 (time-shared)
    unsigned short* ipwb = (unsigned short*)wp; wp += (long)LLY * 3 * EE * EE * 2;
    unsigned short* opwb = (unsigned short*)wp; wp += (long)LLY * EE * EE * 2;
    unsigned short* w1b  = (unsigned short*)wp; wp += (long)LLY * DFF_ * EE * 2;
    unsigned short* w2b  = (unsigned short*)wp; wp += (long)LLY * EE * DFF_ * 2;
    unsigned short* l1wb = (unsigned short*)wp; wp += (long)EE * EE * 2;
    unsigned short* labelb = (unsigned short*)wp; wp += (long)CP * EE * 2;
    unsigned short* fcwb   = (unsigned short*)wp; wp += (long)CP * EE * 2;

    float* out0  = (float*)d_out;                 // [B,C]
    float* attnW = out0 + BB * CC;                // [B,C,S]

    // ---- weight conversion (bf16, row-padded where needed) ----------------
    {
        const long n1 = (long)LLY * 3 * EE * EE;
        cvt_bf16<<<(int)((n1 / 4 + 255) / 256), 256, 0, stream>>>(ipw, ipwb, n1, n1);
        const long n2 = (long)LLY * EE * EE;
        cvt_bf16<<<(int)((n2 / 4 + 255) / 256), 256, 0, stream>>>(opw, opwb, n2, n2);
        const long n3 = (long)LLY * DFF_ * EE;
        cvt_bf16<<<(int)((n3 / 4 + 255) / 256), 256, 0, stream>>>(w1, w1b, n3, n3);
        cvt_bf16<<<(int)((n3 / 4 + 255) / 256), 256, 0, stream>>>(w2, w2b, n3, n3);
        const long n4 = (long)EE * EE;
        cvt_bf16<<<(int)((n4 / 4 + 255) / 256), 256, 0, stream>>>(l1w, l1wb, n4, n4);
        const long n5i = (long)CC * EE, n5o = (long)CP * EE;
        cvt_bf16<<<(int)((n5o / 4 + 255) / 256), 256, 0, stream>>>(label, labelb, n5i, n5o);
        cvt_bf16<<<(int)((n5o / 4 + 255) / 256), 256, 0, stream>>>(fcw, fcwb, n5i, n5o);
    }

    const int M = BB * SS;   // 8192

    embed_kernel<<<4096, 256, 0, stream>>>(inp, pe, x, xb);

    for (int l = 0; l < LLY; ++l) {
        // qkv = x @ ipw^T + ipb -> bf16 big
        gemm_mfma<<<dim3(64, 12, 1), 256, 0, stream>>>(xb, ipwb + (long)l * 3 * EE * EE,
                                                       ipb + l * 3 * EE, nullptr, big,
                                                       M, 3 * EE, EE, M, 0, 0, 0, 0, 2);
        flash_attn<<<dim3(16, 64), 256, 0, stream>>>(big, ob);
        // o @ opw^T + opb -> f32 bufo
        gemm_mfma<<<dim3(64, 4, 1), 256, 0, stream>>>(ob, opwb + (long)l * EE * EE,
                                                      opb + l * EE, bufo, nullptr,
                                                      M, EE, EE, M, 0, 0, 0, 0, 1);
        ln_fused<<<M, 256, 0, stream>>>(x, xb, bufo, g1 + l * EE, b1 + l * EE);
        // ff1 = relu(x @ w1^T + bb1) -> bf16 big
        gemm_mfma<<<dim3(64, 16, 1), 256, 0, stream>>>(xb, w1b + (long)l * DFF_ * EE,
                                                       bb1 + l * DFF_, nullptr, big,
                                                       M, DFF_, EE, M, 0, 0, 0, 1, 2);
        // ff2 = ff1 @ w2^T + bb2 -> f32 bufo
        gemm_mfma<<<dim3(64, 4, 1), 256, 0, stream>>>(big, w2b + (long)l * EE * DFF_,
                                                      bb2 + l * EE, bufo, nullptr,
                                                      M, EE, DFF_, M, 0, 0, 0, 0, 1);
        ln_fused<<<M, 256, 0, stream>>>(x, xb, bufo, g2 + l * EE, b2 + l * EE);
    }

    // o1 = tanh(x @ l1w^T + l1b) -> bf16 ob
    gemm_mfma<<<dim3(64, 4, 1), 256, 0, stream>>>(xb, l1wb, l1b, nullptr, ob,
                                                  M, EE, EE, M, 0, 0, 0, 2, 2);
    // scores[b,c,s] = label[c,:].o1[b,s,:] -> f32 attnW
    gemm_mfma<<<dim3(CP / 128, SS / 128, BB), 256, 0, stream>>>(labelb, ob, nullptr, attnW, nullptr,
                                                                CP, SS, EE, CC,
                                                                0, (long)SS * EE, (long)CC * SS, 0, 1);
    label_softmax<<<BB * CC, 256, 0, stream>>>(attnW);
    init_out<<<(BB * CC + 255) / 256, 256, 0, stream>>>(out0, fcb);
    gemm_label_mfma<<<dim3(CP / 128, SS / 128, BB), 256, 0, stream>>>(fcwb, xb, attnW, out0);
}

// Round 4
// 1231.777 us; speedup vs baseline: 8.0846x; 1.3124x over previous
//
#include <hip/hip_runtime.h>
#include <math.h>

#define BB   8
#define SS   1024
#define EE   512
#define HH   8
#define DHH  64
#define LLY  2
#define CC   8921
#define CP   9088          // C padded to multiple of 128
#define DFF_ 2048

typedef short          bf16x8 __attribute__((ext_vector_type(8)));
typedef float          f32x4  __attribute__((ext_vector_type(4)));
typedef unsigned short u16x4  __attribute__((ext_vector_type(4)));
typedef unsigned short u16x8  __attribute__((ext_vector_type(8)));

__device__ __forceinline__ float bf2f(unsigned short u) {
    return __uint_as_float(((unsigned int)u) << 16);
}
__device__ __forceinline__ unsigned short f2bf(float f) {
    unsigned int u = __float_as_uint(f);
    u = (u + 0x7FFFu + ((u >> 16) & 1u)) >> 16;
    return (unsigned short)u;
}
__device__ __forceinline__ void gload16(const void* g, void* l) {
    __builtin_amdgcn_global_load_lds(
        (const __attribute__((address_space(1))) void*)g,
        (__attribute__((address_space(3))) void*)l, 16, 0, 0);
}

// ---------------------------------------------------------------------------
// f32 -> bf16 convert with zero-pad
// ---------------------------------------------------------------------------
__global__ __launch_bounds__(256) void cvt_bf16(const float* __restrict__ in,
                                                unsigned short* __restrict__ out,
                                                long n_in, long n_out)
{
    const long i4 = ((long)blockIdx.x * 256 + threadIdx.x) * 4;
    if (i4 >= n_out) return;
    u16x4 r;
    if (i4 < n_in) {
        const float4 v = *(const float4*)(in + i4);
        r[0] = f2bf(v.x); r[1] = f2bf(v.y); r[2] = f2bf(v.z); r[3] = f2bf(v.w);
    } else {
        r[0] = r[1] = r[2] = r[3] = 0;
    }
    *(u16x4*)(out + i4) = r;
}

// ---------------------------------------------------------------------------
// embed: x = inputs*sqrt(E) + pe[b]  (pe indexed by batch — source bug kept)
// ---------------------------------------------------------------------------
__global__ __launch_bounds__(256) void embed_kernel(const float* __restrict__ in,
                                                    const float* __restrict__ pe,
                                                    float* __restrict__ x,
                                                    unsigned short* __restrict__ xb)
{
    const long i  = (long)blockIdx.x * 256 + threadIdx.x;
    const int  e4 = (int)(i & 127);
    const int  b  = (int)(i >> 17);
    float4 v = ((const float4*)in)[i];
    const float4 p = ((const float4*)pe)[b * 128 + e4];
    const float sc = 22.627416997969522f;
    v.x = v.x * sc + p.x;  v.y = v.y * sc + p.y;
    v.z = v.z * sc + p.z;  v.w = v.w * sc + p.w;
    ((float4*)x)[i] = v;
    u16x4 h; h[0] = f2bf(v.x); h[1] = f2bf(v.y); h[2] = f2bf(v.z); h[3] = f2bf(v.w);
    ((u16x4*)xb)[i] = h;
}

// ---------------------------------------------------------------------------
// bf16 MFMA GEMM (128x128 tile, BK=64), as in round 3 (passing).
// ---------------------------------------------------------------------------
__global__ __launch_bounds__(256) void gemm_mfma(const unsigned short* __restrict__ A,
                                                 const unsigned short* __restrict__ B,
                                                 const float* __restrict__ bias,
                                                 float* __restrict__ Cf,
                                                 unsigned short* __restrict__ Ch,
                                                 int M, int N, int K, int Mlim,
                                                 long sAz, long sBz, long sCz,
                                                 int act, int mode)
{
    __shared__ unsigned short As[128 * 64];
    __shared__ unsigned short Bs[128 * 64];
    const int t  = threadIdx.x;
    const int wv = t >> 6, ln = t & 63;
    const int wr = wv >> 1, wc = wv & 1;
    const int lr = ln & 15, lg = ln >> 4;
    const int m0 = blockIdx.x * 128, n0 = blockIdx.y * 128;
    const int z  = blockIdx.z;
    const unsigned short* Ab = A + (long)z * sAz;
    const unsigned short* Bb = B + (long)z * sBz;

    const int srow = ln >> 3;
    const int ucol = ((ln & 7) ^ srow) << 3;

    f32x4 acc[4][4];
    #pragma unroll
    for (int i = 0; i < 4; ++i)
        #pragma unroll
        for (int j = 0; j < 4; ++j)
            acc[i][j] = (f32x4){0.f, 0.f, 0.f, 0.f};

    int rA[4], rB[4];
    #pragma unroll
    for (int f = 0; f < 4; ++f) {
        rA[f] = wr * 64 + f * 16 + lr;
        rB[f] = wc * 64 + f * 16 + lr;
    }

    for (int k0 = 0; k0 < K; k0 += 64) {
        __syncthreads();
        #pragma unroll
        for (int c = 0; c < 4; ++c) {
            const int q   = (wv << 2) + c;
            const int row = (q << 3) + srow;
            gload16(Ab + (long)(m0 + row) * K + k0 + ucol, (char*)As + (q << 10));
            gload16(Bb + (long)(n0 + row) * K + k0 + ucol, (char*)Bs + (q << 10));
        }
        __syncthreads();
        #pragma unroll
        for (int kk = 0; kk < 2; ++kk) {
            bf16x8 af[4], bg[4];
            const int s = (kk << 2) + lg;
            #pragma unroll
            for (int f = 0; f < 4; ++f) {
                af[f] = *(const bf16x8*)((const char*)As + rA[f] * 128 + ((s ^ (rA[f] & 7)) << 4));
                bg[f] = *(const bf16x8*)((const char*)Bs + rB[f] * 128 + ((s ^ (rB[f] & 7)) << 4));
            }
            #pragma unroll
            for (int i = 0; i < 4; ++i)
                #pragma unroll
                for (int j = 0; j < 4; ++j)
                    acc[i][j] = __builtin_amdgcn_mfma_f32_16x16x32_bf16(af[i], bg[j], acc[i][j], 0, 0, 0);
        }
    }

    const long zC = (long)z * sCz;
    #pragma unroll
    for (int fm = 0; fm < 4; ++fm) {
        #pragma unroll
        for (int reg = 0; reg < 4; ++reg) {
            const int gm = m0 + wr * 64 + fm * 16 + lg * 4 + reg;
            if (gm >= Mlim) continue;
            #pragma unroll
            for (int fn = 0; fn < 4; ++fn) {
                const int gn = n0 + wc * 64 + fn * 16 + lr;
                float v = acc[fm][fn][reg];
                if (bias) v += bias[gn];
                if (act == 1)      v = fmaxf(v, 0.f);
                else if (act == 2) v = tanhf(v);
                if (mode & 1) Cf[zC + (long)gm * N + gn] = v;
                if (mode & 2) Ch[zC + (long)gm * N + gn] = f2bf(v);
            }
        }
    }
}

// ---------------------------------------------------------------------------
// Fused label-output GEMM (MFMA) — unchanged from round 3.
// ---------------------------------------------------------------------------
__global__ __launch_bounds__(256) void gemm_label_mfma(const unsigned short* __restrict__ A,
                                                       const unsigned short* __restrict__ B,
                                                       const float* __restrict__ attn,
                                                       float* __restrict__ out)
{
    __shared__ unsigned short As[128 * 64];
    __shared__ unsigned short Bs[128 * 64];
    const int t  = threadIdx.x;
    const int wv = t >> 6, ln = t & 63;
    const int wr = wv >> 1, wc = wv & 1;
    const int lr = ln & 15, lg = ln >> 4;
    const int m0 = blockIdx.x * 128, n0 = blockIdx.y * 128;
    const int z  = blockIdx.z;
    const unsigned short* Bb = B + (long)z * SS * EE;

    const int srow = ln >> 3;
    const int ucol = ((ln & 7) ^ srow) << 3;

    f32x4 acc[4][4];
    #pragma unroll
    for (int i = 0; i < 4; ++i)
        #pragma unroll
        for (int j = 0; j < 4; ++j)
            acc[i][j] = (f32x4){0.f, 0.f, 0.f, 0.f};

    int rA[4], rB[4];
    #pragma unroll
    for (int f = 0; f < 4; ++f) {
        rA[f] = wr * 64 + f * 16 + lr;
        rB[f] = wc * 64 + f * 16 + lr;
    }

    for (int k0 = 0; k0 < EE; k0 += 64) {
        __syncthreads();
        #pragma unroll
        for (int c = 0; c < 4; ++c) {
            const int q   = (wv << 2) + c;
            const int row = (q << 3) + srow;
            gload16(A  + (long)(m0 + row) * EE + k0 + ucol, (char*)As + (q << 10));
            gload16(Bb + (long)(n0 + row) * EE + k0 + ucol, (char*)Bs + (q << 10));
        }
        __syncthreads();
        #pragma unroll
        for (int kk = 0; kk < 2; ++kk) {
            bf16x8 af[4], bg[4];
            const int s = (kk << 2) + lg;
            #pragma unroll
            for (int f = 0; f < 4; ++f) {
                af[f] = *(const bf16x8*)((const char*)As + rA[f] * 128 + ((s ^ (rA[f] & 7)) << 4));
                bg[f] = *(const bf16x8*)((const char*)Bs + rB[f] * 128 + ((s ^ (rB[f] & 7)) << 4));
            }
            #pragma unroll
            for (int i = 0; i < 4; ++i)
                #pragma unroll
                for (int j = 0; j < 4; ++j)
                    acc[i][j] = __builtin_amdgcn_mfma_f32_16x16x32_bf16(af[i], bg[j], acc[i][j], 0, 0, 0);
        }
    }

    const float* attb = attn + (long)z * CC * SS;
    float*       outb = out  + (long)z * CC;
    #pragma unroll
    for (int fm = 0; fm < 4; ++fm) {
        #pragma unroll
        for (int reg = 0; reg < 4; ++reg) {
            const int r = m0 + wr * 64 + fm * 16 + lg * 4 + reg;
            float p = 0.f;
            if (r < CC) {
                #pragma unroll
                for (int fn = 0; fn < 4; ++fn) {
                    const int sn = n0 + wc * 64 + fn * 16 + lr;
                    p += acc[fm][fn][reg] * attb[(long)r * SS + sn];
                }
            }
            p += __shfl_xor(p, 1);
            p += __shfl_xor(p, 2);
            p += __shfl_xor(p, 4);
            p += __shfl_xor(p, 8);
            if (lr == 0 && r < CC) atomicAdd(&outb[r], p);
        }
    }
}

// ---------------------------------------------------------------------------
// V transpose: qkv v-part [b,s,(h,d)] -> Vt [bh, d, s]   (bf16)
// ---------------------------------------------------------------------------
__global__ __launch_bounds__(256) void vtrans(const unsigned short* __restrict__ qkv,
                                              unsigned short* __restrict__ Vt)
{
    __shared__ unsigned short tile[64][72];
    const int bh = blockIdx.y, b = bh >> 3, h = bh & 7;
    const int s0 = blockIdx.x << 6;
    const int t  = threadIdx.x;
    const int r  = t >> 3;            // 0..31
    const int c8 = (t & 7) << 3;      // 0,8,..,56
    const unsigned short* vb = qkv + (long)b * SS * 1536 + 2 * EE + h * DHH;
    #pragma unroll
    for (int rr = 0; rr < 64; rr += 32)
        *(u16x8*)&tile[r + rr][c8] = *(const u16x8*)(vb + (long)(s0 + r + rr) * 1536 + c8);
    __syncthreads();
    #pragma unroll
    for (int rr = 0; rr < 64; rr += 32) {
        const int d = r + rr;
        u16x8 o;
        #pragma unroll
        for (int j = 0; j < 8; ++j) o[j] = tile[c8 + j][d];
        *(u16x8*)(Vt + ((long)bh * DHH + d) * SS + s0 + c8) = o;
    }
}

// ---------------------------------------------------------------------------
// MFMA flash attention. Block = (b,h,64 q-rows), 4 waves x 16 q-rows.
// All fragments read directly from global (L2-resident); P re-laid out
// through a per-wave 2KB LDS region with XOR slot swizzle. No __syncthreads.
// Fragment maps (16x16x32): A/B lane: row=ln&15, k=(ln>>4)*8+j;
// C/D lane: row=(ln>>4)*4+reg, col=ln&15.
// ---------------------------------------------------------------------------
__global__ __launch_bounds__(256) void flash_mfma(const unsigned short* __restrict__ qkv,
                                                  const unsigned short* __restrict__ Vt,
                                                  unsigned short* __restrict__ o)
{
    __shared__ unsigned short sP[4][16 * 64];
    const int t  = threadIdx.x;
    const int wv = t >> 6, ln = t & 63;
    const int lr = ln & 15, lg = ln >> 4;
    const int bh = blockIdx.y, b = bh >> 3, h = bh & 7;
    const int q0 = (blockIdx.x << 6) + (wv << 4);

    const unsigned short* qb = qkv + (long)b * SS * 1536 + h * DHH;
    const unsigned short* kb = qb + EE;
    const unsigned short* vt = Vt + (long)bh * DHH * SS;
    unsigned short* pw = sP[wv];

    bf16x8 aq[2];
    #pragma unroll
    for (int c = 0; c < 2; ++c)
        aq[c] = *(const bf16x8*)(qb + (long)(q0 + lr) * 1536 + (c << 5) + (lg << 3));

    float m_[4], l_[4];
    f32x4 accO[4];
    #pragma unroll
    for (int r = 0; r < 4; ++r) { m_[r] = -1e30f; l_[r] = 0.f; }
    #pragma unroll
    for (int n = 0; n < 4; ++n) accO[n] = (f32x4){0.f, 0.f, 0.f, 0.f};

    for (int s0 = 0; s0 < SS; s0 += 64) {
        f32x4 accS[4];
        #pragma unroll
        for (int sj = 0; sj < 4; ++sj) accS[sj] = (f32x4){0.f, 0.f, 0.f, 0.f};
        #pragma unroll
        for (int c = 0; c < 2; ++c) {
            #pragma unroll
            for (int sj = 0; sj < 4; ++sj) {
                const bf16x8 kf = *(const bf16x8*)(kb + (long)(s0 + (sj << 4) + lr) * 1536 + (c << 5) + (lg << 3));
                accS[sj] = __builtin_amdgcn_mfma_f32_16x16x32_bf16(aq[c], kf, accS[sj], 0, 0, 0);
            }
        }
        // online softmax; row q = lg*4+reg spans the 16 lanes sharing lg
        #pragma unroll
        for (int reg = 0; reg < 4; ++reg) {
            float sc0 = accS[0][reg] * 0.125f, sc1 = accS[1][reg] * 0.125f;
            float sc2 = accS[2][reg] * 0.125f, sc3 = accS[3][reg] * 0.125f;
            float mx = fmaxf(fmaxf(sc0, sc1), fmaxf(sc2, sc3));
            mx = fmaxf(mx, __shfl_xor(mx, 1));
            mx = fmaxf(mx, __shfl_xor(mx, 2));
            mx = fmaxf(mx, __shfl_xor(mx, 4));
            mx = fmaxf(mx, __shfl_xor(mx, 8));
            const float mnew = fmaxf(m_[reg], mx);
            const float f = __expf(m_[reg] - mnew);
            m_[reg] = mnew;
            sc0 = __expf(sc0 - mnew); sc1 = __expf(sc1 - mnew);
            sc2 = __expf(sc2 - mnew); sc3 = __expf(sc3 - mnew);
            accS[0][reg] = sc0; accS[1][reg] = sc1;
            accS[2][reg] = sc2; accS[3][reg] = sc3;
            float ss = sc0 + sc1 + sc2 + sc3;
            ss += __shfl_xor(ss, 1); ss += __shfl_xor(ss, 2);
            ss += __shfl_xor(ss, 4); ss += __shfl_xor(ss, 8);
            l_[reg] = l_[reg] * f + ss;
            #pragma unroll
            for (int n = 0; n < 4; ++n) accO[n][reg] *= f;
        }
        // P (D-layout) -> per-wave LDS, bf16, slot-swizzled
        #pragma unroll
        for (int sj = 0; sj < 4; ++sj) {
            #pragma unroll
            for (int reg = 0; reg < 4; ++reg) {
                const int q = (lg << 2) + reg;
                const int s = (sj << 4) + lr;
                const int byte = (q << 7) + (((s >> 3) ^ (q & 7)) << 4) + ((s & 7) << 1);
                *(unsigned short*)((char*)pw + byte) = f2bf(accS[sj][reg]);
            }
        }
        // PV: A-frag of P from LDS, B-frag of V^T from global
        #pragma unroll
        for (int c2 = 0; c2 < 2; ++c2) {
            const int slot = ((c2 << 2) + lg) ^ (lr & 7);
            const bf16x8 pa = *(const bf16x8*)((const char*)pw + (lr << 7) + (slot << 4));
            #pragma unroll
            for (int n = 0; n < 4; ++n) {
                const bf16x8 vf = *(const bf16x8*)(vt + (long)((n << 4) + lr) * SS + s0 + (c2 << 5) + (lg << 3));
                accO[n] = __builtin_amdgcn_mfma_f32_16x16x32_bf16(pa, vf, accO[n], 0, 0, 0);
            }
        }
    }

    #pragma unroll
    for (int reg = 0; reg < 4; ++reg) {
        const float inv = 1.f / l_[reg];
        unsigned short* orow = o + (long)(b * SS + q0 + (lg << 2) + reg) * EE + h * DHH;
        #pragma unroll
        for (int n = 0; n < 4; ++n)
            orow[(n << 4) + lr] = f2bf(accO[n][reg] * inv);
    }
}

// ---------------------------------------------------------------------------
// Fused residual + LayerNorm, in place; also writes bf16 copy.
// ---------------------------------------------------------------------------
__global__ __launch_bounds__(256) void ln_fused(float* __restrict__ x,
                                                unsigned short* __restrict__ xb,
                                                const float* __restrict__ o,
                                                const float* __restrict__ g,
                                                const float* __restrict__ bta)
{
    const long row = blockIdx.x;
    float* xr = x + row * EE;
    unsigned short* hb = xb + row * EE;
    const float* orr = o + row * EE;
    const int t = threadIdx.x;
    const float v0 = xr[t] + orr[t];
    const float v1 = xr[t + 256] + orr[t + 256];
    float s = v0 + v1;
    #pragma unroll
    for (int off = 1; off < 64; off <<= 1) s += __shfl_xor(s, off);
    __shared__ float r1[4], r2[4];
    if ((t & 63) == 0) r1[t >> 6] = s;
    __syncthreads();
    const float mu = (r1[0] + r1[1] + r1[2] + r1[3]) * (1.f / EE);
    const float d0 = v0 - mu, d1 = v1 - mu;
    float q = d0 * d0 + d1 * d1;
    #pragma unroll
    for (int off = 1; off < 64; off <<= 1) q += __shfl_xor(q, off);
    if ((t & 63) == 0) r2[t >> 6] = q;
    __syncthreads();
    const float rs = rsqrtf((r2[0] + r2[1] + r2[2] + r2[3]) * (1.f / EE) + 1e-5f);
    const float y0 = d0 * rs * g[t]       + bta[t];
    const float y1 = d1 * rs * g[t + 256] + bta[t + 256];
    xr[t] = y0;  xr[t + 256] = y1;
    hb[t] = f2bf(y0);  hb[t + 256] = f2bf(y1);
}

// ---------------------------------------------------------------------------
// Label softmax over seq dim: rows = B*C, S=1024
// ---------------------------------------------------------------------------
__global__ __launch_bounds__(256) void label_softmax(float* __restrict__ attn)
{
    const long row = blockIdx.x;
    float* p = attn + row * (long)SS;
    const int t = threadIdx.x;
    float4 v = ((float4*)p)[t];
    __shared__ float red[4];
    float mx = fmaxf(fmaxf(v.x, v.y), fmaxf(v.z, v.w));
    #pragma unroll
    for (int off = 1; off < 64; off <<= 1) mx = fmaxf(mx, __shfl_xor(mx, off));
    if ((t & 63) == 0) red[t >> 6] = mx;
    __syncthreads();
    mx = fmaxf(fmaxf(red[0], red[1]), fmaxf(red[2], red[3]));
    v.x = __expf(v.x - mx); v.y = __expf(v.y - mx);
    v.z = __expf(v.z - mx); v.w = __expf(v.w - mx);
    float s = v.x + v.y + v.z + v.w;
    #pragma unroll
    for (int off = 1; off < 64; off <<= 1) s += __shfl_xor(s, off);
    __syncthreads();
    if ((t & 63) == 0) red[t >> 6] = s;
    __syncthreads();
    const float inv = 1.f / (red[0] + red[1] + red[2] + red[3]);
    v.x *= inv; v.y *= inv; v.z *= inv; v.w *= inv;
    ((float4*)p)[t] = v;
}

__global__ __launch_bounds__(256) void init_out(float* __restrict__ out,
                                                const float* __restrict__ fcb)
{
    const int i = blockIdx.x * 256 + threadIdx.x;
    if (i < BB * CC) out[i] = fcb[i % CC];
}

// ---------------------------------------------------------------------------
extern "C" void kernel_launch(void* const* d_in, const int* in_sizes, int n_in,
                              void* d_out, int out_size, void* d_ws, size_t ws_size,
                              hipStream_t stream)
{
    const float* inp   = (const float*)d_in[0];
    const float* pe    = (const float*)d_in[1];
    const float* label = (const float*)d_in[2];
    const float* l1w   = (const float*)d_in[3];
    const float* l1b   = (const float*)d_in[4];
    const float* fcw   = (const float*)d_in[5];
    const float* fcb   = (const float*)d_in[6];
    const float* ipw   = (const float*)d_in[7];
    const float* ipb   = (const float*)d_in[8];
    const float* opw   = (const float*)d_in[9];
    const float* opb   = (const float*)d_in[10];
    const float* g1    = (const float*)d_in[11];
    const float* b1    = (const float*)d_in[12];
    const float* g2    = (const float*)d_in[13];
    const float* b2    = (const float*)d_in[14];
    const float* w1    = (const float*)d_in[15];
    const float* bb1   = (const float*)d_in[16];
    const float* w2    = (const float*)d_in[17];
    const float* bb2   = (const float*)d_in[18];

    // ---- workspace layout -------------------------------------------------
    char* wp = (char*)d_ws;
    float* x = (float*)wp;                 wp += (long)BB * SS * EE * 4;
    unsigned short* xb = (unsigned short*)wp;  wp += (long)BB * SS * EE * 2;
    float* bufo = (float*)wp;              wp += (long)BB * SS * EE * 4;
    unsigned short* big = (unsigned short*)wp; wp += (long)BB * SS * DFF_ * 2;
    unsigned short* ob  = (unsigned short*)wp; wp += (long)BB * SS * EE * 2;
    unsigned short* Vtb = (unsigned short*)wp; wp += (long)BB * HH * DHH * SS * 2;
    unsigned short* ipwb = (unsigned short*)wp; wp += (long)LLY * 3 * EE * EE * 2;
    unsigned short* opwb = (unsigned short*)wp; wp += (long)LLY * EE * EE * 2;
    unsigned short* w1b  = (unsigned short*)wp; wp += (long)LLY * DFF_ * EE * 2;
    unsigned short* w2b  = (unsigned short*)wp; wp += (long)LLY * EE * DFF_ * 2;
    unsigned short* l1wb = (unsigned short*)wp; wp += (long)EE * EE * 2;
    unsigned short* labelb = (unsigned short*)wp; wp += (long)CP * EE * 2;
    unsigned short* fcwb   = (unsigned short*)wp; wp += (long)CP * EE * 2;

    float* out0  = (float*)d_out;
    float* attnW = out0 + BB * CC;

    {
        const long n1 = (long)LLY * 3 * EE * EE;
        cvt_bf16<<<(int)((n1 / 4 + 255) / 256), 256, 0, stream>>>(ipw, ipwb, n1, n1);
        const long n2 = (long)LLY * EE * EE;
        cvt_bf16<<<(int)((n2 / 4 + 255) / 256), 256, 0, stream>>>(opw, opwb, n2, n2);
        const long n3 = (long)LLY * DFF_ * EE;
        cvt_bf16<<<(int)((n3 / 4 + 255) / 256), 256, 0, stream>>>(w1, w1b, n3, n3);
        cvt_bf16<<<(int)((n3 / 4 + 255) / 256), 256, 0, stream>>>(w2, w2b, n3, n3);
        const long n4 = (long)EE * EE;
        cvt_bf16<<<(int)((n4 / 4 + 255) / 256), 256, 0, stream>>>(l1w, l1wb, n4, n4);
        const long n5i = (long)CC * EE, n5o = (long)CP * EE;
        cvt_bf16<<<(int)((n5o / 4 + 255) / 256), 256, 0, stream>>>(label, labelb, n5i, n5o);
        cvt_bf16<<<(int)((n5o / 4 + 255) / 256), 256, 0, stream>>>(fcw, fcwb, n5i, n5o);
    }

    const int M = BB * SS;   // 8192

    embed_kernel<<<4096, 256, 0, stream>>>(inp, pe, x, xb);

    for (int l = 0; l < LLY; ++l) {
        // qkv = x @ ipw^T + ipb -> bf16 big [M, 1536]
        gemm_mfma<<<dim3(64, 12, 1), 256, 0, stream>>>(xb, ipwb + (long)l * 3 * EE * EE,
                                                       ipb + l * 3 * EE, nullptr, big,
                                                       M, 3 * EE, EE, M, 0, 0, 0, 0, 2);
        vtrans<<<dim3(16, 64), 256, 0, stream>>>(big, Vtb);
        flash_mfma<<<dim3(16, 64), 256, 0, stream>>>(big, Vtb, ob);
        // o @ opw^T + opb -> f32 bufo
        gemm_mfma<<<dim3(64, 4, 1), 256, 0, stream>>>(ob, opwb + (long)l * EE * EE,
                                                      opb + l * EE, bufo, nullptr,
                                                      M, EE, EE, M, 0, 0, 0, 0, 1);
        ln_fused<<<M, 256, 0, stream>>>(x, xb, bufo, g1 + l * EE, b1 + l * EE);
        // ff1 = relu(x @ w1^T + bb1) -> bf16 big
        gemm_mfma<<<dim3(64, 16, 1), 256, 0, stream>>>(xb, w1b + (long)l * DFF_ * EE,
                                                       bb1 + l * DFF_, nullptr, big,
                                                       M, DFF_, EE, M, 0, 0, 0, 1, 2);
        // ff2 = ff1 @ w2^T + bb2 -> f32 bufo
        gemm_mfma<<<dim3(64, 4, 1), 256, 0, stream>>>(big, w2b + (long)l * EE * DFF_,
                                                      bb2 + l * EE, bufo, nullptr,
                                                      M, EE, DFF_, M, 0, 0, 0, 0, 1);
        ln_fused<<<M, 256, 0, stream>>>(x, xb, bufo, g2 + l * EE, b2 + l * EE);
    }

    // o1 = tanh(x @ l1w^T + l1b) -> bf16 ob
    gemm_mfma<<<dim3(64, 4, 1), 256, 0, stream>>>(xb, l1wb, l1b, nullptr, ob,
                                                  M, EE, EE, M, 0, 0, 0, 2, 2);
    // scores[b,c,s] = label[c,:].o1[b,s,:] -> f32 attnW
    gemm_mfma<<<dim3(CP / 128, SS / 128, BB), 256, 0, stream>>>(labelb, ob, nullptr, attnW, nullptr,
                                                                CP, SS, EE, CC,
                                                                0, (long)SS * EE, (long)CC * SS, 0, 1);
    label_softmax<<<BB * CC, 256, 0, stream>>>(attnW);
    init_out<<<(BB * CC + 255) / 256, 256, 0, stream>>>(out0, fcb);
    gemm_label_mfma<<<dim3(CP / 128, SS / 128, BB), 256, 0, stream>>>(fcwb, xb, attnW, out0);
}

// Round 5
// 1100.142 us; speedup vs baseline: 9.0519x; 1.1197x over previous
//
#include <hip/hip_runtime.h>
#include <math.h>

#define BB   8
#define SS   1024
#define EE   512
#define HH   8
#define DHH  64
#define LLY  2
#define CC   8921
#define CP   9088          // C padded to multiple of 128
#define DFF_ 2048

typedef short          bf16x8 __attribute__((ext_vector_type(8)));
typedef float          f32x4  __attribute__((ext_vector_type(4)));
typedef unsigned short u16x4  __attribute__((ext_vector_type(4)));
typedef unsigned short u16x8  __attribute__((ext_vector_type(8)));

__device__ __forceinline__ float bf2f(unsigned short u) {
    return __uint_as_float(((unsigned int)u) << 16);
}
__device__ __forceinline__ unsigned short f2bf(float f) {
    unsigned int u = __float_as_uint(f);
    u = (u + 0x7FFFu + ((u >> 16) & 1u)) >> 16;
    return (unsigned short)u;
}
__device__ __forceinline__ void gload16(const void* g, void* l) {
    __builtin_amdgcn_global_load_lds(
        (const __attribute__((address_space(1))) void*)g,
        (__attribute__((address_space(3))) void*)l, 16, 0, 0);
}

// ---------------------------------------------------------------------------
// f32 -> bf16 convert with zero-pad
// ---------------------------------------------------------------------------
__global__ __launch_bounds__(256) void cvt_bf16(const float* __restrict__ in,
                                                unsigned short* __restrict__ out,
                                                long n_in, long n_out)
{
    const long i4 = ((long)blockIdx.x * 256 + threadIdx.x) * 4;
    if (i4 >= n_out) return;
    u16x4 r;
    if (i4 < n_in) {
        const float4 v = *(const float4*)(in + i4);
        r[0] = f2bf(v.x); r[1] = f2bf(v.y); r[2] = f2bf(v.z); r[3] = f2bf(v.w);
    } else {
        r[0] = r[1] = r[2] = r[3] = 0;
    }
    *(u16x4*)(out + i4) = r;
}

// ---------------------------------------------------------------------------
// embed: x = inputs*sqrt(E) + pe[b]  (pe indexed by batch — source bug kept)
// ---------------------------------------------------------------------------
__global__ __launch_bounds__(256) void embed_kernel(const float* __restrict__ in,
                                                    const float* __restrict__ pe,
                                                    float* __restrict__ x,
                                                    unsigned short* __restrict__ xb)
{
    const long i  = (long)blockIdx.x * 256 + threadIdx.x;
    const int  e4 = (int)(i & 127);
    const int  b  = (int)(i >> 17);
    float4 v = ((const float4*)in)[i];
    const float4 p = ((const float4*)pe)[b * 128 + e4];
    const float sc = 22.627416997969522f;
    v.x = v.x * sc + p.x;  v.y = v.y * sc + p.y;
    v.z = v.z * sc + p.z;  v.w = v.w * sc + p.w;
    ((float4*)x)[i] = v;
    u16x4 h; h[0] = f2bf(v.x); h[1] = f2bf(v.y); h[2] = f2bf(v.z); h[3] = f2bf(v.w);
    ((u16x4*)xb)[i] = h;
}

// ---------------------------------------------------------------------------
// bf16 MFMA GEMM (128x128 tile, BK=64) — verified structure.
// ---------------------------------------------------------------------------
__global__ __launch_bounds__(256) void gemm_mfma(const unsigned short* __restrict__ A,
                                                 const unsigned short* __restrict__ B,
                                                 const float* __restrict__ bias,
                                                 float* __restrict__ Cf,
                                                 unsigned short* __restrict__ Ch,
                                                 int M, int N, int K, int Mlim,
                                                 long sAz, long sBz, long sCz,
                                                 int act, int mode)
{
    __shared__ unsigned short As[128 * 64];
    __shared__ unsigned short Bs[128 * 64];
    const int t  = threadIdx.x;
    const int wv = t >> 6, ln = t & 63;
    const int wr = wv >> 1, wc = wv & 1;
    const int lr = ln & 15, lg = ln >> 4;
    const int m0 = blockIdx.x * 128, n0 = blockIdx.y * 128;
    const int z  = blockIdx.z;
    const unsigned short* Ab = A + (long)z * sAz;
    const unsigned short* Bb = B + (long)z * sBz;

    const int srow = ln >> 3;
    const int ucol = ((ln & 7) ^ srow) << 3;

    f32x4 acc[4][4];
    #pragma unroll
    for (int i = 0; i < 4; ++i)
        #pragma unroll
        for (int j = 0; j < 4; ++j)
            acc[i][j] = (f32x4){0.f, 0.f, 0.f, 0.f};

    int rA[4], rB[4];
    #pragma unroll
    for (int f = 0; f < 4; ++f) {
        rA[f] = wr * 64 + f * 16 + lr;
        rB[f] = wc * 64 + f * 16 + lr;
    }

    for (int k0 = 0; k0 < K; k0 += 64) {
        __syncthreads();
        #pragma unroll
        for (int c = 0; c < 4; ++c) {
            const int q   = (wv << 2) + c;
            const int row = (q << 3) + srow;
            gload16(Ab + (long)(m0 + row) * K + k0 + ucol, (char*)As + (q << 10));
            gload16(Bb + (long)(n0 + row) * K + k0 + ucol, (char*)Bs + (q << 10));
        }
        __syncthreads();
        #pragma unroll
        for (int kk = 0; kk < 2; ++kk) {
            bf16x8 af[4], bg[4];
            const int s = (kk << 2) + lg;
            #pragma unroll
            for (int f = 0; f < 4; ++f) {
                af[f] = *(const bf16x8*)((const char*)As + rA[f] * 128 + ((s ^ (rA[f] & 7)) << 4));
                bg[f] = *(const bf16x8*)((const char*)Bs + rB[f] * 128 + ((s ^ (rB[f] & 7)) << 4));
            }
            #pragma unroll
            for (int i = 0; i < 4; ++i)
                #pragma unroll
                for (int j = 0; j < 4; ++j)
                    acc[i][j] = __builtin_amdgcn_mfma_f32_16x16x32_bf16(af[i], bg[j], acc[i][j], 0, 0, 0);
        }
    }

    const long zC = (long)z * sCz;
    #pragma unroll
    for (int fm = 0; fm < 4; ++fm) {
        #pragma unroll
        for (int reg = 0; reg < 4; ++reg) {
            const int gm = m0 + wr * 64 + fm * 16 + lg * 4 + reg;
            if (gm >= Mlim) continue;
            #pragma unroll
            for (int fn = 0; fn < 4; ++fn) {
                const int gn = n0 + wc * 64 + fn * 16 + lr;
                float v = acc[fm][fn][reg];
                if (bias) v += bias[gn];
                if (act == 1)      v = fmaxf(v, 0.f);
                else if (act == 2) v = tanhf(v);
                if (mode & 1) Cf[zC + (long)gm * N + gn] = v;
                if (mode & 2) Ch[zC + (long)gm * N + gn] = f2bf(v);
            }
        }
    }
}

// ---------------------------------------------------------------------------
// Label scores GEMM + per-row-slice softmax stats.
// raw[c,s] = label[c,:].o1[b,s,:]  -> attnW (f32, raw)
// stats[b,c, y*2+wc] = (max over 64-col slice, sum exp(v-max))
// ---------------------------------------------------------------------------
__global__ __launch_bounds__(256) void gemm_scores(const unsigned short* __restrict__ A,   // labelb [CP,E]
                                                   const unsigned short* __restrict__ B,   // o1b [B*S,E]
                                                   float* __restrict__ attnW,              // [B,CC,S]
                                                   float2* __restrict__ stats)             // [B,CP,16]
{
    __shared__ unsigned short As[128 * 64];
    __shared__ unsigned short Bs[128 * 64];
    const int t  = threadIdx.x;
    const int wv = t >> 6, ln = t & 63;
    const int wr = wv >> 1, wc = wv & 1;
    const int lr = ln & 15, lg = ln >> 4;
    const int m0 = blockIdx.x * 128, n0 = blockIdx.y * 128;
    const int z  = blockIdx.z;
    const unsigned short* Bb = B + (long)z * SS * EE;

    const int srow = ln >> 3;
    const int ucol = ((ln & 7) ^ srow) << 3;

    f32x4 acc[4][4];
    #pragma unroll
    for (int i = 0; i < 4; ++i)
        #pragma unroll
        for (int j = 0; j < 4; ++j)
            acc[i][j] = (f32x4){0.f, 0.f, 0.f, 0.f};

    int rA[4], rB[4];
    #pragma unroll
    for (int f = 0; f < 4; ++f) {
        rA[f] = wr * 64 + f * 16 + lr;
        rB[f] = wc * 64 + f * 16 + lr;
    }

    for (int k0 = 0; k0 < EE; k0 += 64) {
        __syncthreads();
        #pragma unroll
        for (int c = 0; c < 4; ++c) {
            const int q   = (wv << 2) + c;
            const int row = (q << 3) + srow;
            gload16(A  + (long)(m0 + row) * EE + k0 + ucol, (char*)As + (q << 10));
            gload16(Bb + (long)(n0 + row) * EE + k0 + ucol, (char*)Bs + (q << 10));
        }
        __syncthreads();
        #pragma unroll
        for (int kk = 0; kk < 2; ++kk) {
            bf16x8 af[4], bg[4];
            const int s = (kk << 2) + lg;
            #pragma unroll
            for (int f = 0; f < 4; ++f) {
                af[f] = *(const bf16x8*)((const char*)As + rA[f] * 128 + ((s ^ (rA[f] & 7)) << 4));
                bg[f] = *(const bf16x8*)((const char*)Bs + rB[f] * 128 + ((s ^ (rB[f] & 7)) << 4));
            }
            #pragma unroll
            for (int i = 0; i < 4; ++i)
                #pragma unroll
                for (int j = 0; j < 4; ++j)
                    acc[i][j] = __builtin_amdgcn_mfma_f32_16x16x32_bf16(af[i], bg[j], acc[i][j], 0, 0, 0);
        }
    }

    float* aw = attnW + (long)z * CC * SS;
    #pragma unroll
    for (int fm = 0; fm < 4; ++fm) {
        #pragma unroll
        for (int reg = 0; reg < 4; ++reg) {
            const int r = m0 + wr * 64 + fm * 16 + lg * 4 + reg;
            float v0 = acc[fm][0][reg], v1 = acc[fm][1][reg];
            float v2 = acc[fm][2][reg], v3 = acc[fm][3][reg];
            if (r < CC) {
                #pragma unroll
                for (int fn = 0; fn < 4; ++fn) {
                    const int sn = n0 + wc * 64 + fn * 16 + lr;
                    aw[(long)r * SS + sn] = acc[fm][fn][reg];
                }
            }
            // per-64-col-slice stats (16 lanes sharing lg = same row)
            float mx = fmaxf(fmaxf(v0, v1), fmaxf(v2, v3));
            mx = fmaxf(mx, __shfl_xor(mx, 1));
            mx = fmaxf(mx, __shfl_xor(mx, 2));
            mx = fmaxf(mx, __shfl_xor(mx, 4));
            mx = fmaxf(mx, __shfl_xor(mx, 8));
            float sm = __expf(v0 - mx) + __expf(v1 - mx) + __expf(v2 - mx) + __expf(v3 - mx);
            sm += __shfl_xor(sm, 1); sm += __shfl_xor(sm, 2);
            sm += __shfl_xor(sm, 4); sm += __shfl_xor(sm, 8);
            if (lr == 0 && r < CC)
                stats[((long)z * CP + r) * 16 + blockIdx.y * 2 + wc] = make_float2(mx, sm);
        }
    }
}

// ---------------------------------------------------------------------------
// merge 16 slice-stats per row -> (max, 1/sum)
// ---------------------------------------------------------------------------
__global__ __launch_bounds__(256) void merge_stats(const float2* __restrict__ stats,
                                                   float2* __restrict__ rowstat)
{
    const long idx = (long)blockIdx.x * 256 + threadIdx.x;   // z*CP + c
    if (idx >= (long)BB * CP) return;
    const int c = (int)(idx % CP);
    if (c >= CC) return;
    const float2* s = stats + idx * 16;
    float mx = -1e30f;
    #pragma unroll
    for (int i = 0; i < 16; ++i) mx = fmaxf(mx, s[i].x);
    float tot = 0.f;
    #pragma unroll
    for (int i = 0; i < 16; ++i) tot += s[i].y * __expf(s[i].x - mx);
    rowstat[idx] = make_float2(mx, 1.f / tot);
}

// ---------------------------------------------------------------------------
// Fused final: D[c,s] = fcw[c,:].x[b,s,:] (MFMA);
// p = exp(raw-mx)*inv  -> rewrite attnW in place (block-exclusive tile);
// out[b,c] += sum_s p * D[c,s]
// ---------------------------------------------------------------------------
__global__ __launch_bounds__(256) void gemm_label_final(const unsigned short* __restrict__ A,  // fcwb [CP,E]
                                                        const unsigned short* __restrict__ B,  // xb [B*S,E]
                                                        float* __restrict__ attnW,             // [B,CC,S] raw->p
                                                        const float2* __restrict__ rowstat,    // [B,CP]
                                                        float* __restrict__ out)               // [B,C]
{
    __shared__ unsigned short As[128 * 64];
    __shared__ unsigned short Bs[128 * 64];
    const int t  = threadIdx.x;
    const int wv = t >> 6, ln = t & 63;
    const int wr = wv >> 1, wc = wv & 1;
    const int lr = ln & 15, lg = ln >> 4;
    const int m0 = blockIdx.x * 128, n0 = blockIdx.y * 128;
    const int z  = blockIdx.z;
    const unsigned short* Bb = B + (long)z * SS * EE;

    const int srow = ln >> 3;
    const int ucol = ((ln & 7) ^ srow) << 3;

    f32x4 acc[4][4];
    #pragma unroll
    for (int i = 0; i < 4; ++i)
        #pragma unroll
        for (int j = 0; j < 4; ++j)
            acc[i][j] = (f32x4){0.f, 0.f, 0.f, 0.f};

    int rA[4], rB[4];
    #pragma unroll
    for (int f = 0; f < 4; ++f) {
        rA[f] = wr * 64 + f * 16 + lr;
        rB[f] = wc * 64 + f * 16 + lr;
    }

    for (int k0 = 0; k0 < EE; k0 += 64) {
        __syncthreads();
        #pragma unroll
        for (int c = 0; c < 4; ++c) {
            const int q   = (wv << 2) + c;
            const int row = (q << 3) + srow;
            gload16(A  + (long)(m0 + row) * EE + k0 + ucol, (char*)As + (q << 10));
            gload16(Bb + (long)(n0 + row) * EE + k0 + ucol, (char*)Bs + (q << 10));
        }
        __syncthreads();
        #pragma unroll
        for (int kk = 0; kk < 2; ++kk) {
            bf16x8 af[4], bg[4];
            const int s = (kk << 2) + lg;
            #pragma unroll
            for (int f = 0; f < 4; ++f) {
                af[f] = *(const bf16x8*)((const char*)As + rA[f] * 128 + ((s ^ (rA[f] & 7)) << 4));
                bg[f] = *(const bf16x8*)((const char*)Bs + rB[f] * 128 + ((s ^ (rB[f] & 7)) << 4));
            }
            #pragma unroll
            for (int i = 0; i < 4; ++i)
                #pragma unroll
                for (int j = 0; j < 4; ++j)
                    acc[i][j] = __builtin_amdgcn_mfma_f32_16x16x32_bf16(af[i], bg[j], acc[i][j], 0, 0, 0);
        }
    }

    float* aw = attnW + (long)z * CC * SS;
    const float2* rs = rowstat + (long)z * CP;
    float* outb = out + (long)z * CC;
    #pragma unroll
    for (int fm = 0; fm < 4; ++fm) {
        #pragma unroll
        for (int reg = 0; reg < 4; ++reg) {
            const int r = m0 + wr * 64 + fm * 16 + lg * 4 + reg;
            float pacc = 0.f;
            if (r < CC) {
                const float2 st = rs[r];
                #pragma unroll
                for (int fn = 0; fn < 4; ++fn) {
                    const int sn = n0 + wc * 64 + fn * 16 + lr;
                    const float raw = aw[(long)r * SS + sn];
                    const float p = __expf(raw - st.x) * st.y;
                    aw[(long)r * SS + sn] = p;
                    pacc += p * acc[fm][fn][reg];
                }
            }
            pacc += __shfl_xor(pacc, 1);
            pacc += __shfl_xor(pacc, 2);
            pacc += __shfl_xor(pacc, 4);
            pacc += __shfl_xor(pacc, 8);
            if (lr == 0 && r < CC) atomicAdd(&outb[r], pacc);
        }
    }
}

// ---------------------------------------------------------------------------
// V transpose: qkv v-part [b,s,(h,d)] -> Vt [bh, d, s]   (bf16)
// ---------------------------------------------------------------------------
__global__ __launch_bounds__(256) void vtrans(const unsigned short* __restrict__ qkv,
                                              unsigned short* __restrict__ Vt)
{
    __shared__ unsigned short tile[64][72];
    const int bh = blockIdx.y, b = bh >> 3, h = bh & 7;
    const int s0 = blockIdx.x << 6;
    const int t  = threadIdx.x;
    const int r  = t >> 3;
    const int c8 = (t & 7) << 3;
    const unsigned short* vb = qkv + (long)b * SS * 1536 + 2 * EE + h * DHH;
    #pragma unroll
    for (int rr = 0; rr < 64; rr += 32)
        *(u16x8*)&tile[r + rr][c8] = *(const u16x8*)(vb + (long)(s0 + r + rr) * 1536 + c8);
    __syncthreads();
    #pragma unroll
    for (int rr = 0; rr < 64; rr += 32) {
        const int d = r + rr;
        u16x8 o;
        #pragma unroll
        for (int j = 0; j < 8; ++j) o[j] = tile[c8 + j][d];
        *(u16x8*)(Vt + ((long)bh * DHH + d) * SS + s0 + c8) = o;
    }
}

// ---------------------------------------------------------------------------
// MFMA flash attention v2: K/V tiles staged in LDS via global_load_lds with
// the gemm swizzle scheme (conflict-free ds_read_b128 fragments).
// Block = (b,h,64 q-rows), 4 waves x 16 q-rows. P via per-wave LDS.
// ---------------------------------------------------------------------------
__global__ __launch_bounds__(256) void flash_mfma(const unsigned short* __restrict__ qkv,
                                                  const unsigned short* __restrict__ Vt,
                                                  unsigned short* __restrict__ o)
{
    __shared__ unsigned short sK[64 * 64];      // K tile [s][d], swizzled
    __shared__ unsigned short sV[64 * 64];      // Vt tile [d][s], swizzled
    __shared__ unsigned short sP[4][16 * 64];   // per-wave P tile
    const int t  = threadIdx.x;
    const int wv = t >> 6, ln = t & 63;
    const int lr = ln & 15, lg = ln >> 4;
    const int bh = blockIdx.y, b = bh >> 3, h = bh & 7;
    const int q0 = (blockIdx.x << 6) + (wv << 4);

    const unsigned short* qb = qkv + (long)b * SS * 1536 + h * DHH;
    const unsigned short* kb = qb + EE;
    const unsigned short* vt = Vt + (long)bh * DHH * SS;
    unsigned short* pw = sP[wv];

    const int srow = ln >> 3;                   // staging row within 8-row chunk
    const int ucol = ((ln & 7) ^ srow) << 3;    // pre-swizzled source col (elems)

    bf16x8 aq[2];
    #pragma unroll
    for (int c = 0; c < 2; ++c)
        aq[c] = *(const bf16x8*)(qb + (long)(q0 + lr) * 1536 + (c << 5) + (lg << 3));

    float m_[4], l_[4];
    f32x4 accO[4];
    #pragma unroll
    for (int r = 0; r < 4; ++r) { m_[r] = -1e30f; l_[r] = 0.f; }
    #pragma unroll
    for (int n = 0; n < 4; ++n) accO[n] = (f32x4){0.f, 0.f, 0.f, 0.f};

    for (int s0 = 0; s0 < SS; s0 += 64) {
        __syncthreads();   // prev-iter sK/sV reads done
        #pragma unroll
        for (int c = 0; c < 2; ++c) {
            const int row = (wv << 4) + (c << 3) + srow;     // 16 rows per wave
            gload16(kb + (long)(s0 + row) * 1536 + ucol, (char*)sK + (((wv << 1) + c) << 10));
            gload16(vt + (long)row * SS + s0 + ucol,     (char*)sV + (((wv << 1) + c) << 10));
        }
        __syncthreads();

        // QK^T: B-frag = K rows sj*16+lr, k-chunk slot c*4+lg
        f32x4 accS[4];
        #pragma unroll
        for (int sj = 0; sj < 4; ++sj) accS[sj] = (f32x4){0.f, 0.f, 0.f, 0.f};
        #pragma unroll
        for (int c = 0; c < 2; ++c) {
            const int slot = (c << 2) + lg;
            #pragma unroll
            for (int sj = 0; sj < 4; ++sj) {
                const int rw = (sj << 4) + lr;
                const bf16x8 kf = *(const bf16x8*)((const char*)sK + rw * 128 + ((slot ^ (rw & 7)) << 4));
                accS[sj] = __builtin_amdgcn_mfma_f32_16x16x32_bf16(aq[c], kf, accS[sj], 0, 0, 0);
            }
        }
        // online softmax (rows = lg*4+reg; 16 lanes share a row)
        #pragma unroll
        for (int reg = 0; reg < 4; ++reg) {
            float sc0 = accS[0][reg] * 0.125f, sc1 = accS[1][reg] * 0.125f;
            float sc2 = accS[2][reg] * 0.125f, sc3 = accS[3][reg] * 0.125f;
            float mx = fmaxf(fmaxf(sc0, sc1), fmaxf(sc2, sc3));
            mx = fmaxf(mx, __shfl_xor(mx, 1));
            mx = fmaxf(mx, __shfl_xor(mx, 2));
            mx = fmaxf(mx, __shfl_xor(mx, 4));
            mx = fmaxf(mx, __shfl_xor(mx, 8));
            const float mnew = fmaxf(m_[reg], mx);
            const float f = __expf(m_[reg] - mnew);
            m_[reg] = mnew;
            sc0 = __expf(sc0 - mnew); sc1 = __expf(sc1 - mnew);
            sc2 = __expf(sc2 - mnew); sc3 = __expf(sc3 - mnew);
            accS[0][reg] = sc0; accS[1][reg] = sc1;
            accS[2][reg] = sc2; accS[3][reg] = sc3;
            float ss = sc0 + sc1 + sc2 + sc3;
            ss += __shfl_xor(ss, 1); ss += __shfl_xor(ss, 2);
            ss += __shfl_xor(ss, 4); ss += __shfl_xor(ss, 8);
            l_[reg] = l_[reg] * f + ss;
            #pragma unroll
            for (int n = 0; n < 4; ++n) accO[n][reg] *= f;
        }
        // P (D-layout) -> per-wave LDS, bf16, slot-swizzled
        #pragma unroll
        for (int sj = 0; sj < 4; ++sj) {
            #pragma unroll
            for (int reg = 0; reg < 4; ++reg) {
                const int q = (lg << 2) + reg;
                const int s = (sj << 4) + lr;
                const int byte = (q << 7) + (((s >> 3) ^ (q & 7)) << 4) + ((s & 7) << 1);
                *(unsigned short*)((char*)pw + byte) = f2bf(accS[sj][reg]);
            }
        }
        // PV: A-frag of P from LDS, B-frag of V from sV
        #pragma unroll
        for (int c2 = 0; c2 < 2; ++c2) {
            const int pslot = ((c2 << 2) + lg) ^ (lr & 7);
            const bf16x8 pa = *(const bf16x8*)((const char*)pw + (lr << 7) + (pslot << 4));
            const int vslot = (c2 << 2) + lg;
            #pragma unroll
            for (int n = 0; n < 4; ++n) {
                const int rw = (n << 4) + lr;
                const bf16x8 vf = *(const bf16x8*)((const char*)sV + rw * 128 + ((vslot ^ (rw & 7)) << 4));
                accO[n] = __builtin_amdgcn_mfma_f32_16x16x32_bf16(pa, vf, accO[n], 0, 0, 0);
            }
        }
    }

    #pragma unroll
    for (int reg = 0; reg < 4; ++reg) {
        const float inv = 1.f / l_[reg];
        unsigned short* orow = o + (long)(b * SS + q0 + (lg << 2) + reg) * EE + h * DHH;
        #pragma unroll
        for (int n = 0; n < 4; ++n)
            orow[(n << 4) + lr] = f2bf(accO[n][reg] * inv);
    }
}

// ---------------------------------------------------------------------------
// Fused residual + LayerNorm, in place; also writes bf16 copy.
// ---------------------------------------------------------------------------
__global__ __launch_bounds__(256) void ln_fused(float* __restrict__ x,
                                                unsigned short* __restrict__ xb,
                                                const float* __restrict__ o,
                                                const float* __restrict__ g,
                                                const float* __restrict__ bta)
{
    const long row = blockIdx.x;
    float* xr = x + row * EE;
    unsigned short* hb = xb + row * EE;
    const float* orr = o + row * EE;
    const int t = threadIdx.x;
    const float v0 = xr[t] + orr[t];
    const float v1 = xr[t + 256] + orr[t + 256];
    float s = v0 + v1;
    #pragma unroll
    for (int off = 1; off < 64; off <<= 1) s += __shfl_xor(s, off);
    __shared__ float r1[4], r2[4];
    if ((t & 63) == 0) r1[t >> 6] = s;
    __syncthreads();
    const float mu = (r1[0] + r1[1] + r1[2] + r1[3]) * (1.f / EE);
    const float d0 = v0 - mu, d1 = v1 - mu;
    float q = d0 * d0 + d1 * d1;
    #pragma unroll
    for (int off = 1; off < 64; off <<= 1) q += __shfl_xor(q, off);
    if ((t & 63) == 0) r2[t >> 6] = q;
    __syncthreads();
    const float rs = rsqrtf((r2[0] + r2[1] + r2[2] + r2[3]) * (1.f / EE) + 1e-5f);
    const float y0 = d0 * rs * g[t]       + bta[t];
    const float y1 = d1 * rs * g[t + 256] + bta[t + 256];
    xr[t] = y0;  xr[t + 256] = y1;
    hb[t] = f2bf(y0);  hb[t + 256] = f2bf(y1);
}

__global__ __launch_bounds__(256) void init_out(float* __restrict__ out,
                                                const float* __restrict__ fcb)
{
    const int i = blockIdx.x * 256 + threadIdx.x;
    if (i < BB * CC) out[i] = fcb[i % CC];
}

// ---------------------------------------------------------------------------
extern "C" void kernel_launch(void* const* d_in, const int* in_sizes, int n_in,
                              void* d_out, int out_size, void* d_ws, size_t ws_size,
                              hipStream_t stream)
{
    const float* inp   = (const float*)d_in[0];
    const float* pe    = (const float*)d_in[1];
    const float* label = (const float*)d_in[2];
    const float* l1w   = (const float*)d_in[3];
    const float* l1b   = (const float*)d_in[4];
    const float* fcw   = (const float*)d_in[5];
    const float* fcb   = (const float*)d_in[6];
    const float* ipw   = (const float*)d_in[7];
    const float* ipb   = (const float*)d_in[8];
    const float* opw   = (const float*)d_in[9];
    const float* opb   = (const float*)d_in[10];
    const float* g1    = (const float*)d_in[11];
    const float* b1    = (const float*)d_in[12];
    const float* g2    = (const float*)d_in[13];
    const float* b2    = (const float*)d_in[14];
    const float* w1    = (const float*)d_in[15];
    const float* bb1   = (const float*)d_in[16];
    const float* w2    = (const float*)d_in[17];
    const float* bb2   = (const float*)d_in[18];

    // ---- workspace layout -------------------------------------------------
    char* wp = (char*)d_ws;
    float* x = (float*)wp;                 wp += (long)BB * SS * EE * 4;
    unsigned short* xb = (unsigned short*)wp;  wp += (long)BB * SS * EE * 2;
    float* bufo = (float*)wp;              wp += (long)BB * SS * EE * 4;
    unsigned short* big = (unsigned short*)wp; wp += (long)BB * SS * DFF_ * 2;
    unsigned short* ob  = (unsigned short*)wp; wp += (long)BB * SS * EE * 2;
    unsigned short* Vtb = (unsigned short*)wp; wp += (long)BB * HH * DHH * SS * 2;
    unsigned short* ipwb = (unsigned short*)wp; wp += (long)LLY * 3 * EE * EE * 2;
    unsigned short* opwb = (unsigned short*)wp; wp += (long)LLY * EE * EE * 2;
    unsigned short* w1b  = (unsigned short*)wp; wp += (long)LLY * DFF_ * EE * 2;
    unsigned short* w2b  = (unsigned short*)wp; wp += (long)LLY * EE * DFF_ * 2;
    unsigned short* l1wb = (unsigned short*)wp; wp += (long)EE * EE * 2;
    unsigned short* labelb = (unsigned short*)wp; wp += (long)CP * EE * 2;
    unsigned short* fcwb   = (unsigned short*)wp; wp += (long)CP * EE * 2;
    float2* stats   = (float2*)wp;         wp += (long)BB * CP * 16 * 8;
    float2* rowstat = (float2*)wp;         wp += (long)BB * CP * 8;

    float* out0  = (float*)d_out;
    float* attnW = out0 + BB * CC;

    {
        const long n1 = (long)LLY * 3 * EE * EE;
        cvt_bf16<<<(int)((n1 / 4 + 255) / 256), 256, 0, stream>>>(ipw, ipwb, n1, n1);
        const long n2 = (long)LLY * EE * EE;
        cvt_bf16<<<(int)((n2 / 4 + 255) / 256), 256, 0, stream>>>(opw, opwb, n2, n2);
        const long n3 = (long)LLY * DFF_ * EE;
        cvt_bf16<<<(int)((n3 / 4 + 255) / 256), 256, 0, stream>>>(w1, w1b, n3, n3);
        cvt_bf16<<<(int)((n3 / 4 + 255) / 256), 256, 0, stream>>>(w2, w2b, n3, n3);
        const long n4 = (long)EE * EE;
        cvt_bf16<<<(int)((n4 / 4 + 255) / 256), 256, 0, stream>>>(l1w, l1wb, n4, n4);
        const long n5i = (long)CC * EE, n5o = (long)CP * EE;
        cvt_bf16<<<(int)((n5o / 4 + 255) / 256), 256, 0, stream>>>(label, labelb, n5i, n5o);
        cvt_bf16<<<(int)((n5o / 4 + 255) / 256), 256, 0, stream>>>(fcw, fcwb, n5i, n5o);
    }

    const int M = BB * SS;   // 8192

    embed_kernel<<<4096, 256, 0, stream>>>(inp, pe, x, xb);

    for (int l = 0; l < LLY; ++l) {
        gemm_mfma<<<dim3(64, 12, 1), 256, 0, stream>>>(xb, ipwb + (long)l * 3 * EE * EE,
                                                       ipb + l * 3 * EE, nullptr, big,
                                                       M, 3 * EE, EE, M, 0, 0, 0, 0, 2);
        vtrans<<<dim3(16, 64), 256, 0, stream>>>(big, Vtb);
        flash_mfma<<<dim3(16, 64), 256, 0, stream>>>(big, Vtb, ob);
        gemm_mfma<<<dim3(64, 4, 1), 256, 0, stream>>>(ob, opwb + (long)l * EE * EE,
                                                      opb + l * EE, bufo, nullptr,
                                                      M, EE, EE, M, 0, 0, 0, 0, 1);
        ln_fused<<<M, 256, 0, stream>>>(x, xb, bufo, g1 + l * EE, b1 + l * EE);
        gemm_mfma<<<dim3(64, 16, 1), 256, 0, stream>>>(xb, w1b + (long)l * DFF_ * EE,
                                                       bb1 + l * DFF_, nullptr, big,
                                                       M, DFF_, EE, M, 0, 0, 0, 1, 2);
        gemm_mfma<<<dim3(64, 4, 1), 256, 0, stream>>>(big, w2b + (long)l * EE * DFF_,
                                                      bb2 + l * EE, bufo, nullptr,
                                                      M, EE, DFF_, M, 0, 0, 0, 0, 1);
        ln_fused<<<M, 256, 0, stream>>>(x, xb, bufo, g2 + l * EE, b2 + l * EE);
    }

    // o1 = tanh(x @ l1w^T + l1b) -> bf16 ob
    gemm_mfma<<<dim3(64, 4, 1), 256, 0, stream>>>(xb, l1wb, l1b, nullptr, ob,
                                                  M, EE, EE, M, 0, 0, 0, 2, 2);
    // raw scores + slice stats
    gemm_scores<<<dim3(CP / 128, SS / 128, BB), 256, 0, stream>>>(labelb, ob, attnW, stats);
    merge_stats<<<(int)(((long)BB * CP + 255) / 256), 256, 0, stream>>>(stats, rowstat);
    init_out<<<(BB * CC + 255) / 256, 256, 0, stream>>>(out0, fcb);
    // fused: D-GEMM + softmax-normalize (in place) + weighted reduce
    gemm_label_final<<<dim3(CP / 128, SS / 128, BB), 256, 0, stream>>>(fcwb, xb, attnW, rowstat, out0);
}